// Round 10
// baseline (317.256 us; speedup 1.0000x reference)
//
#include <hip/hip_runtime.h>
#include <math.h>

#define N_NODES 2048
#define D_MODEL 256
#define D_FEAT 128
#define NHEAD 8
#define DH 32
#define NLAYER 2
#define NEDGE 65536
#define D_FF 1024
#define D_OUT 128
#define MAXDEG 512
#define JSPLIT 4

typedef __attribute__((ext_vector_type(8))) short short8;
typedef __attribute__((ext_vector_type(4))) float f32x4;
typedef __attribute__((ext_vector_type(4))) unsigned short u16x4;

__device__ __forceinline__ unsigned short f2bf(float f) {
    unsigned u = __float_as_uint(f);
    unsigned r = (u + 0x7FFFu + ((u >> 16) & 1u)) >> 16;
    return (unsigned short)r;
}

// ---------------- mega prep: bucket table + zeroing + all weight transposes ----------------
__device__ __forceinline__ void wt_tile(const float* __restrict__ W, unsigned short* __restrict__ Wt,
                                        int K, int Nc, int n0, int k0, int tid,
                                        unsigned short (*tile)[33]) {
    int r = tid >> 3, cg = (tid & 7) * 4;
    float4 w4 = *(const float4*)&W[(size_t)(k0 + r) * Nc + n0 + cg];
    tile[r][cg + 0] = f2bf(w4.x); tile[r][cg + 1] = f2bf(w4.y);
    tile[r][cg + 2] = f2bf(w4.z); tile[r][cg + 3] = f2bf(w4.w);
    __syncthreads();
    int c = tid >> 3, rg = (tid & 7) * 4;
    u16x4 o;
    #pragma unroll
    for (int j = 0; j < 4; j++) o[j] = tile[rg + j][c];
    *(u16x4*)&Wt[(size_t)(n0 + c) * K + k0 + rg] = o;
}

__global__ void mega_prep_kernel(const float* __restrict__ pos, unsigned char* __restrict__ bucket,
                                 unsigned* __restrict__ hist, int* __restrict__ deg_out,
                                 int* __restrict__ deg_in, unsigned* __restrict__ gcursor,
                                 const float* __restrict__ Wq, const float* __restrict__ Wk,
                                 const float* __restrict__ Wv, const float* __restrict__ Wo,
                                 const float* __restrict__ W1, const float* __restrict__ W2,
                                 const float* __restrict__ W_emb, const float* __restrict__ W_out,
                                 const float* __restrict__ bq, const float* __restrict__ bk,
                                 const float* __restrict__ bv,
                                 unsigned short* __restrict__ qkvt, unsigned short* __restrict__ wot,
                                 unsigned short* __restrict__ w1t, unsigned short* __restrict__ w2t,
                                 unsigned short* __restrict__ wembt, unsigned short* __restrict__ woutt,
                                 float* __restrict__ bqkv) {
    __shared__ unsigned short tile[32][33];
    int b = blockIdx.x, tid = threadIdx.x;
    if (b < 4096) {
        int i = b * 256 + tid;
        float4 p = *(const float4*)&pos[(size_t)i * 4];
        unsigned b0 = (unsigned)fminf(fmaxf(p.x * 10.f + 0.5f, 0.f), 10.f);
        unsigned b1 = (unsigned)fminf(fmaxf(p.y * 10.f + 0.5f, 0.f), 10.f);
        unsigned b2 = (unsigned)fminf(fmaxf(p.z * 10.f + 0.5f, 0.f), 10.f);
        unsigned b3 = (unsigned)fminf(fmaxf(p.w * 10.f + 0.5f, 0.f), 10.f);
        ((unsigned*)bucket)[i] = b0 | (b1 << 8) | (b2 << 16) | (b3 << 24);
        if (b < 64) {
            #pragma unroll
            for (int k = 0; k < 4; k++) hist[b * 1024 + k * 256 + tid] = 0;
        } else if (b == 64) {
            #pragma unroll
            for (int k = 0; k < 8; k++) deg_out[k * 256 + tid] = 0;
            #pragma unroll
            for (int k = 0; k < 8; k++) deg_in[k * 256 + tid] = 0;
            if (tid == 0) *gcursor = 0;
        }
        return;
    }
    int bb = b - 4096;
    if (bb < 512) {
        int z = bb >> 6, t = bb & 63;
        int l = z >> 2, which = z & 3;
        const float* W = (which == 0 ? Wq : which == 1 ? Wk : which == 2 ? Wv : Wo) + (size_t)l * 65536;
        unsigned short* dst = (which < 3) ? qkvt + (size_t)l * 196608 + which * 65536
                                          : wot + (size_t)l * 65536;
        wt_tile(W, dst, 256, 256, (t & 7) * 32, (t >> 3) * 32, tid, tile);
    } else if (bb < 1024) {
        int b2 = bb - 512, l = b2 >> 8, t = b2 & 255;
        wt_tile(W1 + (size_t)l * D_MODEL * D_FF, w1t + (size_t)l * D_MODEL * D_FF,
                D_MODEL, D_FF, (t & 31) * 32, (t >> 5) * 32, tid, tile);
    } else if (bb < 1536) {
        int b3 = bb - 1024, l = b3 >> 8, t = b3 & 255;
        wt_tile(W2 + (size_t)l * D_FF * D_MODEL, w2t + (size_t)l * D_FF * D_MODEL,
                D_FF, D_MODEL, (t & 7) * 32, (t >> 3) * 32, tid, tile);
    } else if (bb < 1568) {
        int b4 = bb - 1536;
        wt_tile(W_emb, wembt, D_FEAT, D_MODEL, (b4 & 7) * 32, (b4 >> 3) * 32, tid, tile);
    } else if (bb < 1600) {
        int b5 = bb - 1568;
        wt_tile(W_out, woutt, D_MODEL, D_OUT, (b5 & 3) * 32, (b5 >> 2) * 32, tid, tile);
    } else {
        int i = (bb - 1600) * 256 + tid;
        if (i < NLAYER * 768) {
            int l = i / 768, j = i % 768;
            const float* src = j < 256 ? bq : j < 512 ? bk : bv;
            bqkv[i] = src[l * 256 + (j & 255)];
        }
    }
}

// ---------------- degree + edge histogram ----------------
__global__ void degree_hist_kernel(const int* __restrict__ ei,
                                   int* __restrict__ deg_out, int* __restrict__ deg_in,
                                   unsigned* __restrict__ hist) {
    int e = blockIdx.x * 256 + threadIdx.x;
    if (e < NEDGE) {
        int src = ei[e], dst = ei[NEDGE + e];
        atomicAdd(&deg_out[src], 1);
        atomicAdd(&deg_in[dst], 1);
        atomicAdd(&hist[(src >> 6) * 2048 + dst], 1);
    }
}

// ---------------- single-kernel slab allocator (per-64-key-group slabs) ----------------
__global__ void edge_alloc_kernel(const unsigned* __restrict__ hist,
                                  unsigned* __restrict__ offsets, unsigned* __restrict__ cursor,
                                  unsigned* __restrict__ gend, unsigned* __restrict__ gcursor) {
    int g = blockIdx.x;
    int t = threadIdx.x;
    unsigned v = hist[g * 64 + t];
    unsigned inc = v;
    #pragma unroll
    for (int off = 1; off < 64; off <<= 1) {
        unsigned u = __shfl_up(inc, off);
        if (t >= off) inc += u;
    }
    unsigned total = __shfl(inc, 63);
    unsigned base = 0;
    if (t == 63) base = atomicAdd(gcursor, total);
    base = __shfl(base, 63);
    unsigned o = base + inc - v;
    offsets[g * 64 + t] = o;
    cursor[g * 64 + t] = o;
    if (t == 63) gend[g] = base + total;
}

__global__ void edge_scatter_kernel(const int* __restrict__ ei, const int* __restrict__ etypes,
                                    unsigned* __restrict__ cursor, unsigned* __restrict__ packed) {
    int e = blockIdx.x * 256 + threadIdx.x;
    if (e < NEDGE) {
        int src = ei[e], dst = ei[NEDGE + e];
        int key = (src >> 6) * 2048 + dst;
        unsigned pos = atomicAdd(&cursor[key], 1);
        packed[pos] = (unsigned)dst | ((unsigned)(src & 63) << 11) | ((unsigned)etypes[e] << 17);
    }
}

// ---------------- fused centrality + layernorm1 ----------------
__global__ void centrality_ln_kernel(float* __restrict__ h,
                                     const float* __restrict__ din_l,
                                     const float* __restrict__ dout_l,
                                     const int* __restrict__ deg_in,
                                     const int* __restrict__ deg_out,
                                     const float* __restrict__ g,
                                     const float* __restrict__ b,
                                     unsigned short* __restrict__ y) {
    int row = blockIdx.x;
    int tid = threadIdx.x;
    int di = min(max(deg_in[row], 0), MAXDEG);
    int dn = min(max(deg_out[row], 0), MAXDEG);
    float v = h[row * D_MODEL + tid] + din_l[di * D_MODEL + tid] + dout_l[dn * D_MODEL + tid];
    h[row * D_MODEL + tid] = v;
    __shared__ float red[256];
    red[tid] = v; __syncthreads();
    for (int s = 128; s > 0; s >>= 1) { if (tid < s) red[tid] += red[tid + s]; __syncthreads(); }
    float mu = red[0] * (1.0f / D_MODEL);
    __syncthreads();
    float d = v - mu;
    red[tid] = d * d; __syncthreads();
    for (int s = 128; s > 0; s >>= 1) { if (tid < s) red[tid] += red[tid + s]; __syncthreads(); }
    float rstd = rsqrtf(red[0] * (1.0f / D_MODEL) + 1e-5f);
    y[row * D_MODEL + tid] = f2bf(d * rstd * g[tid] + b[tid]);
}

// ---------------- layernorm2 ----------------
__global__ void layernorm_kernel(const float* __restrict__ x,
                                 const float* __restrict__ g,
                                 const float* __restrict__ b,
                                 unsigned short* __restrict__ y) {
    int row = blockIdx.x;
    int tid = threadIdx.x;
    float v = x[row * D_MODEL + tid];
    __shared__ float red[256];
    red[tid] = v; __syncthreads();
    for (int s = 128; s > 0; s >>= 1) { if (tid < s) red[tid] += red[tid + s]; __syncthreads(); }
    float mu = red[0] * (1.0f / D_MODEL);
    __syncthreads();
    float d = v - mu;
    red[tid] = d * d; __syncthreads();
    for (int s = 128; s > 0; s >>= 1) { if (tid < s) red[tid] += red[tid + s]; __syncthreads(); }
    float rstd = rsqrtf(red[0] * (1.0f / D_MODEL) + 1e-5f);
    y[row * D_MODEL + tid] = f2bf(d * rstd * g[tid] + b[tid]);
}

// ---------------- bf16 MFMA GEMM, 32x64 tile, prefetched K-loop ----------------
template <int ACT, bool RESID, bool OUTBF16, bool AFP32>
__global__ void gemm_mfma_kernel(const void* __restrict__ Av,
                                 const unsigned short* __restrict__ Wt,
                                 const float* __restrict__ bias,
                                 float* __restrict__ C, unsigned short* __restrict__ Cb,
                                 int Nc, int K) {
    __shared__ __align__(16) unsigned short As[32][72];
    __shared__ __align__(16) unsigned short Bs[64][72];
    const unsigned short* A16 = (const unsigned short*)Av;
    const float* A32 = (const float*)Av;
    int tid = threadIdx.x;
    int m0 = blockIdx.y * 32, n0 = blockIdx.x * 64;
    int w = tid >> 6, lane = tid & 63;
    int rg = (w & 1) * 16, cg = (w >> 1) * 32;
    int m = lane & 15, quad = lane >> 4;
    f32x4 acc[2] = {{0.f, 0.f, 0.f, 0.f}, {0.f, 0.f, 0.f, 0.f}};
    int ar = tid >> 3, ac = (tid & 7) * 8;
    uint4 ra; float4 fa0, fa1; uint4 rb0, rb1;
    if (AFP32) {
        fa0 = *(const float4*)&A32[(size_t)(m0 + ar) * K + ac];
        fa1 = *(const float4*)&A32[(size_t)(m0 + ar) * K + ac + 4];
    } else {
        ra = *(const uint4*)&A16[(size_t)(m0 + ar) * K + ac];
    }
    rb0 = *(const uint4*)&Wt[(size_t)(n0 + ar) * K + ac];
    rb1 = *(const uint4*)&Wt[(size_t)(n0 + 32 + ar) * K + ac];
    for (int k0 = 0; k0 < K; k0 += 64) {
        if (AFP32) {
            u16x4 t0 = {f2bf(fa0.x), f2bf(fa0.y), f2bf(fa0.z), f2bf(fa0.w)};
            u16x4 t1 = {f2bf(fa1.x), f2bf(fa1.y), f2bf(fa1.z), f2bf(fa1.w)};
            *(u16x4*)&As[ar][ac] = t0;
            *(u16x4*)&As[ar][ac + 4] = t1;
        } else {
            *(uint4*)&As[ar][ac] = ra;
        }
        *(uint4*)&Bs[ar][ac] = rb0;
        *(uint4*)&Bs[ar + 32][ac] = rb1;
        __syncthreads();
        int kn = k0 + 64;
        if (kn < K) {
            if (AFP32) {
                fa0 = *(const float4*)&A32[(size_t)(m0 + ar) * K + kn + ac];
                fa1 = *(const float4*)&A32[(size_t)(m0 + ar) * K + kn + ac + 4];
            } else {
                ra = *(const uint4*)&A16[(size_t)(m0 + ar) * K + kn + ac];
            }
            rb0 = *(const uint4*)&Wt[(size_t)(n0 + ar) * K + kn + ac];
            rb1 = *(const uint4*)&Wt[(size_t)(n0 + 32 + ar) * K + kn + ac];
        }
        #pragma unroll
        for (int ks = 0; ks < 2; ks++) {
            short8 a = *(const short8*)&As[rg + m][ks * 32 + quad * 8];
            #pragma unroll
            for (int t = 0; t < 2; t++) {
                short8 b = *(const short8*)&Bs[cg + t * 16 + m][ks * 32 + quad * 8];
                acc[t] = __builtin_amdgcn_mfma_f32_16x16x32_bf16(a, b, acc[t], 0, 0, 0);
            }
        }
        __syncthreads();
    }
    #pragma unroll
    for (int t = 0; t < 2; t++) {
        #pragma unroll
        for (int reg = 0; reg < 4; reg++) {
            int row = m0 + rg + quad * 4 + reg;
            int col = n0 + cg + t * 16 + m;
            float val = acc[t][reg] + bias[col];
            if (ACT == 1) val = val * 0.5f * (1.0f + erff(val * 0.7071067811865476f));
            size_t idx = (size_t)row * Nc + col;
            if (RESID) val += C[idx];
            if (OUTBF16) Cb[idx] = f2bf(val);
            else C[idx] = val;
        }
    }
}

// ---------------- QKV GEMM: 32x64 tile (3 blocks/CU), Q/K -> qkvb; V-region (n0>=512)
// transposed through LDS and stored coalesced into vbt[dh][node] ----------------
__global__ void gemm_qkv_kernel(const unsigned short* __restrict__ A,
                                const unsigned short* __restrict__ Wt,
                                const float* __restrict__ bias,
                                unsigned short* __restrict__ Cb,
                                unsigned short* __restrict__ vbt) {
    const int K = D_MODEL, Nc = 768;
    __shared__ __align__(16) unsigned short As[32][72];
    __shared__ __align__(16) unsigned short Bs[64][72];
    int tid = threadIdx.x;
    int m0 = blockIdx.y * 32, n0 = blockIdx.x * 64;
    int w = tid >> 6, lane = tid & 63;
    int rg = (w & 1) * 16, cg = (w >> 1) * 32;
    int m = lane & 15, quad = lane >> 4;
    f32x4 acc[2] = {{0.f, 0.f, 0.f, 0.f}, {0.f, 0.f, 0.f, 0.f}};
    int ar = tid >> 3, ac = (tid & 7) * 8;
    uint4 ra = *(const uint4*)&A[(size_t)(m0 + ar) * K + ac];
    uint4 rb0 = *(const uint4*)&Wt[(size_t)(n0 + ar) * K + ac];
    uint4 rb1 = *(const uint4*)&Wt[(size_t)(n0 + 32 + ar) * K + ac];
    for (int k0 = 0; k0 < K; k0 += 64) {
        *(uint4*)&As[ar][ac] = ra;
        *(uint4*)&Bs[ar][ac] = rb0;
        *(uint4*)&Bs[ar + 32][ac] = rb1;
        __syncthreads();
        int kn = k0 + 64;
        if (kn < K) {
            ra = *(const uint4*)&A[(size_t)(m0 + ar) * K + kn + ac];
            rb0 = *(const uint4*)&Wt[(size_t)(n0 + ar) * K + kn + ac];
            rb1 = *(const uint4*)&Wt[(size_t)(n0 + 32 + ar) * K + kn + ac];
        }
        #pragma unroll
        for (int ks = 0; ks < 2; ks++) {
            short8 a = *(const short8*)&As[rg + m][ks * 32 + quad * 8];
            #pragma unroll
            for (int t = 0; t < 2; t++) {
                short8 b = *(const short8*)&Bs[cg + t * 16 + m][ks * 32 + quad * 8];
                acc[t] = __builtin_amdgcn_mfma_f32_16x16x32_bf16(a, b, acc[t], 0, 0, 0);
            }
        }
        __syncthreads();
    }
    if (n0 >= 512) {
        // V region: transpose through Bs (free after final barrier), coalesced store to vbt
        #pragma unroll
        for (int t = 0; t < 2; t++) {
            int cl = cg + t * 16 + m;                   // local col = V dim within tile
            float bcol = bias[n0 + cl];
            u16x4 tv;
            #pragma unroll
            for (int reg = 0; reg < 4; reg++) tv[reg] = f2bf(acc[t][reg] + bcol);
            *(u16x4*)&Bs[cl][rg + quad * 4] = tv;       // Bs[local col][local row]
        }
        __syncthreads();
        int rr = tid >> 2, cc = (tid & 3) * 8;
        uint4 o0 = *(const uint4*)&Bs[rr][cc];
        *(uint4*)&vbt[(size_t)(n0 - 512 + rr) * N_NODES + m0 + cc] = o0;
        return;
    }
    #pragma unroll
    for (int t = 0; t < 2; t++) {
        #pragma unroll
        for (int reg = 0; reg < 4; reg++) {
            int row = m0 + rg + quad * 4 + reg;
            int col = n0 + cg + t * 16 + m;
            Cb[(size_t)row * Nc + col] = f2bf(acc[t][reg] + bias[col]);
        }
    }
}

// ---------------- O-proj GEMM with in-staging merge: h += (ΣO/Σl) @ Wo + bo ----------------
__global__ void gemm_oproj_kernel(const float* __restrict__ part_O,
                                  const float* __restrict__ l_part,
                                  const unsigned short* __restrict__ Wt,
                                  const float* __restrict__ bias,
                                  float* __restrict__ C) {
    __shared__ __align__(16) unsigned short As[32][72];
    __shared__ __align__(16) unsigned short Bs[64][72];
    int tid = threadIdx.x;
    int m0 = blockIdx.y * 32, n0 = blockIdx.x * 64;
    int w = tid >> 6, lane = tid & 63;
    int rg = (w & 1) * 16, cg = (w >> 1) * 32;
    int m = lane & 15, quad = lane >> 4;
    f32x4 acc[2] = {{0.f, 0.f, 0.f, 0.f}, {0.f, 0.f, 0.f, 0.f}};
    int ar = tid >> 3, ac = (tid & 7) * 8;
    int row = m0 + ar;
    for (int k0 = 0; k0 < D_MODEL; k0 += 64) {
        int col = k0 + ac;
        int hh = col >> 5;
        float L = 0.f;
        float o[8] = {0.f, 0.f, 0.f, 0.f, 0.f, 0.f, 0.f, 0.f};
        #pragma unroll
        for (int js = 0; js < JSPLIT; js++) {
            L += l_part[((size_t)js * NHEAD + hh) * N_NODES + row];
            const float* pp = &part_O[((size_t)js * N_NODES + row) * D_MODEL + col];
            float4 p0 = *(const float4*)pp;
            float4 p1 = *(const float4*)(pp + 4);
            o[0] += p0.x; o[1] += p0.y; o[2] += p0.z; o[3] += p0.w;
            o[4] += p1.x; o[5] += p1.y; o[6] += p1.z; o[7] += p1.w;
        }
        float inv = 1.0f / L;
        u16x4 t0, t1;
        #pragma unroll
        for (int j = 0; j < 4; j++) { t0[j] = f2bf(o[j] * inv); t1[j] = f2bf(o[j + 4] * inv); }
        *(u16x4*)&As[ar][ac] = t0;
        *(u16x4*)&As[ar][ac + 4] = t1;
        *(uint4*)&Bs[ar][ac] = *(const uint4*)&Wt[(size_t)(n0 + ar) * D_MODEL + k0 + ac];
        *(uint4*)&Bs[ar + 32][ac] = *(const uint4*)&Wt[(size_t)(n0 + 32 + ar) * D_MODEL + k0 + ac];
        __syncthreads();
        #pragma unroll
        for (int ks = 0; ks < 2; ks++) {
            short8 a = *(const short8*)&As[rg + m][ks * 32 + quad * 8];
            #pragma unroll
            for (int t = 0; t < 2; t++) {
                short8 b = *(const short8*)&Bs[cg + t * 16 + m][ks * 32 + quad * 8];
                acc[t] = __builtin_amdgcn_mfma_f32_16x16x32_bf16(a, b, acc[t], 0, 0, 0);
            }
        }
        __syncthreads();
    }
    #pragma unroll
    for (int t = 0; t < 2; t++) {
        #pragma unroll
        for (int reg = 0; reg < 4; reg++) {
            int orow = m0 + rg + quad * 4 + reg;
            int ocol = n0 + cg + t * 16 + m;
            size_t idx = (size_t)orow * D_MODEL + ocol;
            C[idx] += acc[t][reg] + bias[ocol];
        }
    }
}

// ---------------- flash attention v4: swapped QK^T (P lane-local per q-row) ----------------
// mfma(K, Q) puts P[q=r0+m][k=16t+4quad+r] in-lane: bias reads become f32x4, P packs to bf16
// dwords written into the SAME ov row storage (bias consumed) and read back as the exact PV
// A-fragment (2 b128). XOR col-swizzle ((row&7)<<2) on ov breaks row-stride conflicts; applied
// uniformly to expand/atomics/bias/P. 2 barriers/tile; K/V double-buffered (v3 structure).
// grid (N/64, H, JSPLIT), block 256 = 4 waves; wave w owns rows w*16..+16.
__global__ __launch_bounds__(256)
void flash_attn_kernel(const unsigned short* __restrict__ qkvb,
                       const unsigned short* __restrict__ vbt,
                       const unsigned char* __restrict__ bucket,
                       const float* __restrict__ spd_l,
                       const float* __restrict__ et_l,
                       const unsigned* __restrict__ offsets,
                       const unsigned* __restrict__ gend,
                       const unsigned* __restrict__ packed,
                       float* __restrict__ part_O,
                       float* __restrict__ l_part) {
    __shared__ __align__(16) unsigned short ks[2][64][40];
    __shared__ __align__(16) unsigned short vs[2][32][72];
    __shared__ __align__(16) float ov[64][68];
    __shared__ float et[8];

    int tid = threadIdx.x;
    int rb = blockIdx.x;
    int i0 = rb * 64;
    int hh = blockIdx.y;
    int js = blockIdx.z;
    int lane = tid & 63;
    if (tid < 8) et[tid] = et_l[tid * NHEAD + hh];
    float spd_reg = spd_l[(lane < 11 ? lane : 10) * NHEAD + hh];

    int w = tid >> 6;
    int m = lane & 15, quad = lane >> 4;
    int r0 = w * 16;
    short8 aq = *(const short8*)&qkvb[(size_t)(i0 + r0 + m) * 768 + hh * DH + quad * 8];
    float l_acc = 0.f;
    f32x4 oacc[2] = {{0.f, 0.f, 0.f, 0.f}, {0.f, 0.f, 0.f, 0.f}};
    const float scale = 0.17677669529663687f;
    const int NT = N_NODES / JSPLIT / 64;

    int krow = tid >> 2, kcol = (tid & 3) * 8;
    int vrow = tid >> 3, vcol = (tid & 7) * 8;
    int erow = r0 + (lane >> 2);          // wave-private SPD expand: own 16 rows
    int ecol = (lane & 3) * 16;
    int eswz = (erow & 7) << 2;           // ov col xor-swizzle for expand rows
    int cswz = (m & 7) << 2;              // ov col xor-swizzle for compute row r0+m

    int jbase = js * (N_NODES / JSPLIT);
    // tile 0: load + stage + expand (own rows, swizzled cols)
    uint4 kpre = *(const uint4*)&qkvb[(size_t)(jbase + krow) * 768 + 256 + hh * DH + kcol];
    uint4 vpre = *(const uint4*)&vbt[(size_t)(hh * DH + vrow) * N_NODES + jbase + vcol];
    uint4 bpre = *(const uint4*)&bucket[(size_t)(i0 + erow) * N_NODES + jbase + ecol];
    *(uint4*)&ks[0][krow][kcol] = kpre;
    *(uint4*)&vs[0][vrow][vcol] = vpre;
    {
        const unsigned char* bb = (const unsigned char*)&bpre;
        #pragma unroll
        for (int g = 0; g < 4; g++) {
            f32x4 st;
            #pragma unroll
            for (int i2 = 0; i2 < 4; i2++)
                st[i2] = __int_as_float(__builtin_amdgcn_ds_bpermute(
                    ((int)bb[g * 4 + i2]) << 2, __float_as_int(spd_reg)));
            *(f32x4*)&ov[erow][(ecol + g * 4) ^ eswz] = st;
        }
    }

    int buf = 0;
    for (int jt = 0; jt < NT; jt++) {
        int j0 = jbase + jt * 64;
        __syncthreads();                    // B1: staging + own-row expansion visible to all
        // ---- cross-wave phase: per-edge bias scatter-add (swizzled col) ----
        {
            unsigned key0 = (unsigned)rb * 2048 + j0;
            unsigned start = offsets[key0], end = gend[key0 >> 6];
            for (unsigned i = start + tid; i < end; i += 256) {
                unsigned p = packed[i];
                int arow = (p >> 11) & 63;
                int acol = ((p & 2047) - j0) ^ ((arow & 7) << 2);
                atomicAdd(&ov[arow][acol], et[(p >> 17) & 7]);
            }
        }
        // prefetch next tile during the atomic phase
        if (jt + 1 < NT) {
            int jn = j0 + 64;
            kpre = *(const uint4*)&qkvb[(size_t)(jn + krow) * 768 + 256 + hh * DH + kcol];
            vpre = *(const uint4*)&vbt[(size_t)(hh * DH + vrow) * N_NODES + jn + vcol];
            bpre = *(const uint4*)&bucket[(size_t)(i0 + erow) * N_NODES + jn + ecol];
        }
        __syncthreads();                    // B2: atomics complete
        // ---- wave-private phase: swapped QK (P row lane-local), bias f32x4, exp ----
        float sv[4][4];
        #pragma unroll
        for (int t = 0; t < 4; t++) {
            short8 bk8 = *(const short8*)&ks[buf][t * 16 + m][quad * 8];
            f32x4 z = {0.f, 0.f, 0.f, 0.f};
            // swapped: A=K rows (16t+m), B=Q rows (r0+m): D[k=4quad+r][q=m]
            f32x4 sacc = __builtin_amdgcn_mfma_f32_16x16x32_bf16(bk8, aq, z, 0, 0, 0);
            f32x4 bv = *(const f32x4*)&ov[r0 + m][(t * 16 + quad * 4) ^ cswz];
            #pragma unroll
            for (int r = 0; r < 4; r++) {
                float pv = __expf(sacc[r] * scale + bv[r]);
                sv[t][r] = pv;
                l_acc += pv;
            }
        }
        // pack P to bf16 dwords into own ov row (bias already consumed), swizzled dword cols
        unsigned* ovrow = (unsigned*)&ov[r0 + m][0];
        #pragma unroll
        for (int t = 0; t < 4; t++) {
            #pragma unroll
            for (int rp = 0; rp < 2; rp++) {
                unsigned d = (unsigned)f2bf(sv[t][2 * rp]) |
                             ((unsigned)f2bf(sv[t][2 * rp + 1]) << 16);
                ovrow[(8 * t + 2 * quad + rp) ^ cswz] = d;
            }
        }
        __builtin_amdgcn_s_waitcnt(0xC07F);   // lgkmcnt(0): own-row pack writes complete
        #pragma unroll
        for (int kh = 0; kh < 2; kh++) {
            uint4 pd = *(const uint4*)&ovrow[(16 * kh + 4 * quad) ^ cswz];
            short8 pa = *(short8*)&pd;
            #pragma unroll
            for (int t = 0; t < 2; t++) {
                short8 vb = *(const short8*)&vs[buf][t * 16 + m][kh * 32 + quad * 8];
                oacc[t] = __builtin_amdgcn_mfma_f32_16x16x32_bf16(pa, vb, oacc[t], 0, 0, 0);
            }
        }
        // stage next tile + expand next SPD into own ov rows (overwrites P remnants).
        // Safe without a barrier: ks/vs -> buf^1 (no current readers); ov writes touch only
        // OWN rows whose last readers (this wave's P b128 reads) already completed in-order.
        if (jt + 1 < NT) {
            *(uint4*)&ks[buf ^ 1][krow][kcol] = kpre;
            *(uint4*)&vs[buf ^ 1][vrow][vcol] = vpre;
            const unsigned char* bb = (const unsigned char*)&bpre;
            #pragma unroll
            for (int g = 0; g < 4; g++) {
                f32x4 st;
                #pragma unroll
                for (int i2 = 0; i2 < 4; i2++)
                    st[i2] = __int_as_float(__builtin_amdgcn_ds_bpermute(
                        ((int)bb[g * 4 + i2]) << 2, __float_as_int(spd_reg)));
                *(f32x4*)&ov[erow][(ecol + g * 4) ^ eswz] = st;
            }
            buf ^= 1;
        }
    }
    #pragma unroll
    for (int t = 0; t < 2; t++)
        #pragma unroll
        for (int r = 0; r < 4; r++)
            part_O[((size_t)js * N_NODES + i0 + r0 + quad * 4 + r) * D_MODEL + hh * DH + t * 16 + m] =
                oacc[t][r];
    // l reduction: lanes {m, m+16, m+32, m+48} hold partials for q-row r0+m
    l_acc += __int_as_float(__builtin_amdgcn_ds_bpermute((lane ^ 16) << 2, __float_as_int(l_acc)));
    l_acc += __int_as_float(__builtin_amdgcn_ds_bpermute((lane ^ 32) << 2, __float_as_int(l_acc)));
    if (quad == 0)
        l_part[((size_t)js * NHEAD + hh) * N_NODES + i0 + r0 + m] = l_acc;
}

// 256-byte-aligned workspace allocation
#define WS_ALLOC(type, name, count) \
    type* name = (type*)base; base += (((size_t)(count) * sizeof(type)) + 255) & ~(size_t)255;

extern "C" void kernel_launch(void* const* d_in, const int* in_sizes, int n_in,
                              void* d_out, int out_size, void* d_ws, size_t ws_size,
                              hipStream_t stream) {
    const float* x          = (const float*)d_in[0];
    const int*   edge_index = (const int*)d_in[1];
    const int*   edge_types = (const int*)d_in[2];
    const float* pos        = (const float*)d_in[3];
    const float* W_emb      = (const float*)d_in[4];
    const float* b_emb      = (const float*)d_in[5];
    const float* Wq         = (const float*)d_in[6];
    const float* Wk         = (const float*)d_in[7];
    const float* Wv         = (const float*)d_in[8];
    const float* Wo         = (const float*)d_in[9];
    const float* bq         = (const float*)d_in[10];
    const float* bk         = (const float*)d_in[11];
    const float* bv         = (const float*)d_in[12];
    const float* bo         = (const float*)d_in[13];
    const float* spd_table  = (const float*)d_in[14];
    const float* edge_table = (const float*)d_in[15];
    const float* din_emb    = (const float*)d_in[16];
    const float* dout_emb   = (const float*)d_in[17];
    const float* ln1_g      = (const float*)d_in[18];
    const float* ln1_b      = (const float*)d_in[19];
    const float* ln2_g      = (const float*)d_in[20];
    const float* ln2_b      = (const float*)d_in[21];
    const float* W1         = (const float*)d_in[22];
    const float* b1         = (const float*)d_in[23];
    const float* W2         = (const float*)d_in[24];
    const float* b2         = (const float*)d_in[25];
    const float* W_out      = (const float*)d_in[26];
    const float* b_out      = (const float*)d_in[27];
    float* out = (float*)d_out;

    char* base = (char*)d_ws;
    WS_ALLOC(int, deg_out, N_NODES)
    WS_ALLOC(int, deg_in, N_NODES)
    WS_ALLOC(float, h, N_NODES * D_MODEL)
    WS_ALLOC(unsigned short, xb, N_NODES * D_MODEL)
    WS_ALLOC(unsigned short, qkvb, N_NODES * 768)
    WS_ALLOC(unsigned short, vbt, D_MODEL * N_NODES)
    WS_ALLOC(unsigned short, ffnb, N_NODES * D_FF)
    WS_ALLOC(unsigned char, bucket, (size_t)N_NODES * N_NODES)
    WS_ALLOC(unsigned short, qkvt, NLAYER * 768 * D_MODEL)
    WS_ALLOC(unsigned short, wot, NLAYER * D_MODEL * D_MODEL)
    WS_ALLOC(unsigned short, w1t, NLAYER * D_MODEL * D_FF)
    WS_ALLOC(unsigned short, w2t, NLAYER * D_FF * D_MODEL)
    WS_ALLOC(unsigned short, wembt, D_FEAT * D_MODEL)
    WS_ALLOC(unsigned short, woutt, D_MODEL * D_OUT)
    WS_ALLOC(float, bqkv, NLAYER * 768)
    WS_ALLOC(unsigned, hist, 65536)
    WS_ALLOC(unsigned, offsets, 65536)
    WS_ALLOC(unsigned, cursor, 65536)
    WS_ALLOC(unsigned, gend, 1024)
    WS_ALLOC(unsigned, gcursor, 1)
    WS_ALLOC(unsigned, packed, NEDGE)
    WS_ALLOC(float, part_O, (size_t)JSPLIT * N_NODES * D_MODEL)
    WS_ALLOC(float, l_part, (size_t)JSPLIT * NHEAD * N_NODES)

    // ---- prep ----
    mega_prep_kernel<<<5702, 256, 0, stream>>>(pos, bucket, hist, deg_out, deg_in, gcursor,
                                               Wq, Wk, Wv, Wo, W1, W2, W_emb, W_out,
                                               bq, bk, bv, qkvt, wot, w1t, w2t, wembt, woutt, bqkv);
    degree_hist_kernel<<<NEDGE / 256, 256, 0, stream>>>(edge_index, deg_out, deg_in, hist);
    edge_alloc_kernel<<<1024, 64, 0, stream>>>(hist, offsets, cursor, gend, gcursor);
    edge_scatter_kernel<<<NEDGE / 256, 256, 0, stream>>>(edge_index, edge_types, cursor, packed);

    // embed: h = x @ W_emb + b_emb (fp32 A, cast in staging)
    gemm_mfma_kernel<0, false, false, true><<<dim3(D_MODEL / 64, N_NODES / 32), 256, 0, stream>>>(
        x, wembt, b_emb, h, nullptr, D_MODEL, D_FEAT);

    for (int l = 0; l < NLAYER; l++) {
        centrality_ln_kernel<<<N_NODES, 256, 0, stream>>>(
            h, din_emb + (size_t)l * (MAXDEG + 1) * D_MODEL,
            dout_emb + (size_t)l * (MAXDEG + 1) * D_MODEL, deg_in, deg_out,
            ln1_g + l * D_MODEL, ln1_b + l * D_MODEL, xb);

        // QKV gemm, 32x64 tile (768 blocks = 3/CU); V-region -> vbt via LDS transpose
        gemm_qkv_kernel<<<dim3(768 / 64, N_NODES / 32), 256, 0, stream>>>(
            xb, qkvt + (size_t)l * 768 * D_MODEL, bqkv + l * 768, qkvb, vbt);

        flash_attn_kernel<<<dim3(N_NODES / 64, NHEAD, JSPLIT), 256, 0, stream>>>(
            qkvb, vbt, bucket, spd_table + (size_t)l * 11 * NHEAD,
            edge_table + (size_t)l * 8 * NHEAD, offsets, gend, packed, part_O, l_part);

        gemm_oproj_kernel<<<dim3(D_MODEL / 64, N_NODES / 32), 256, 0, stream>>>(
            part_O, l_part, wot + (size_t)l * D_MODEL * D_MODEL, bo + l * D_MODEL, h);

        layernorm_kernel<<<N_NODES, 256, 0, stream>>>(h, ln2_g + l * D_MODEL, ln2_b + l * D_MODEL, xb);

        // FFN1, 32x64 tile (1024 blocks = 4/CU), GELU, bf16 out
        gemm_mfma_kernel<1, false, true, false><<<dim3(D_FF / 64, N_NODES / 32), 256, 0, stream>>>(
            xb, w1t + (size_t)l * D_MODEL * D_FF, b1 + l * D_FF, nullptr, ffnb, D_FF, D_MODEL);

        gemm_mfma_kernel<0, true, false, false><<<dim3(D_MODEL / 64, N_NODES / 32), 256, 0, stream>>>(
            ffnb, w2t + (size_t)l * D_FF * D_MODEL, b2 + l * D_MODEL, h, nullptr, D_MODEL, D_FF);
    }

    // final: out = h @ W_out + b_out (fp32 A, cast in staging)
    gemm_mfma_kernel<0, false, false, true><<<dim3(D_OUT / 64, N_NODES / 32), 256, 0, stream>>>(
        h, woutt, b_out, out, nullptr, D_OUT, D_MODEL);
}

// Round 11
// 295.641 us; speedup vs baseline: 1.0731x; 1.0731x over previous
//
#include <hip/hip_runtime.h>
#include <math.h>

#define N_NODES 2048
#define D_MODEL 256
#define D_FEAT 128
#define NHEAD 8
#define DH 32
#define NLAYER 2
#define NEDGE 65536
#define D_FF 1024
#define D_OUT 128
#define MAXDEG 512
#define JSPLIT 4

typedef __attribute__((ext_vector_type(8))) short short8;
typedef __attribute__((ext_vector_type(4))) float f32x4;
typedef __attribute__((ext_vector_type(4))) unsigned short u16x4;

__device__ __forceinline__ unsigned short f2bf(float f) {
    unsigned u = __float_as_uint(f);
    unsigned r = (u + 0x7FFFu + ((u >> 16) & 1u)) >> 16;
    return (unsigned short)r;
}

// ---------------- mega prep: bucket table + zeroing + all weight transposes ----------------
__device__ __forceinline__ void wt_tile(const float* __restrict__ W, unsigned short* __restrict__ Wt,
                                        int K, int Nc, int n0, int k0, int tid,
                                        unsigned short (*tile)[33]) {
    int r = tid >> 3, cg = (tid & 7) * 4;
    float4 w4 = *(const float4*)&W[(size_t)(k0 + r) * Nc + n0 + cg];
    tile[r][cg + 0] = f2bf(w4.x); tile[r][cg + 1] = f2bf(w4.y);
    tile[r][cg + 2] = f2bf(w4.z); tile[r][cg + 3] = f2bf(w4.w);
    __syncthreads();
    int c = tid >> 3, rg = (tid & 7) * 4;
    u16x4 o;
    #pragma unroll
    for (int j = 0; j < 4; j++) o[j] = tile[rg + j][c];
    *(u16x4*)&Wt[(size_t)(n0 + c) * K + k0 + rg] = o;
}

__global__ void mega_prep_kernel(const float* __restrict__ pos, unsigned char* __restrict__ bucket,
                                 unsigned* __restrict__ hist, int* __restrict__ deg_out,
                                 int* __restrict__ deg_in, unsigned* __restrict__ gcursor,
                                 const float* __restrict__ Wq, const float* __restrict__ Wk,
                                 const float* __restrict__ Wv, const float* __restrict__ Wo,
                                 const float* __restrict__ W1, const float* __restrict__ W2,
                                 const float* __restrict__ W_emb, const float* __restrict__ W_out,
                                 const float* __restrict__ bq, const float* __restrict__ bk,
                                 const float* __restrict__ bv,
                                 unsigned short* __restrict__ qkvt, unsigned short* __restrict__ wot,
                                 unsigned short* __restrict__ w1t, unsigned short* __restrict__ w2t,
                                 unsigned short* __restrict__ wembt, unsigned short* __restrict__ woutt,
                                 float* __restrict__ bqkv) {
    __shared__ unsigned short tile[32][33];
    int b = blockIdx.x, tid = threadIdx.x;
    if (b < 4096) {
        int i = b * 256 + tid;
        float4 p = *(const float4*)&pos[(size_t)i * 4];
        unsigned b0 = (unsigned)fminf(fmaxf(p.x * 10.f + 0.5f, 0.f), 10.f);
        unsigned b1 = (unsigned)fminf(fmaxf(p.y * 10.f + 0.5f, 0.f), 10.f);
        unsigned b2 = (unsigned)fminf(fmaxf(p.z * 10.f + 0.5f, 0.f), 10.f);
        unsigned b3 = (unsigned)fminf(fmaxf(p.w * 10.f + 0.5f, 0.f), 10.f);
        ((unsigned*)bucket)[i] = b0 | (b1 << 8) | (b2 << 16) | (b3 << 24);
        if (b < 64) {
            #pragma unroll
            for (int k = 0; k < 4; k++) hist[b * 1024 + k * 256 + tid] = 0;
        } else if (b == 64) {
            #pragma unroll
            for (int k = 0; k < 8; k++) deg_out[k * 256 + tid] = 0;
            #pragma unroll
            for (int k = 0; k < 8; k++) deg_in[k * 256 + tid] = 0;
            if (tid == 0) *gcursor = 0;
        }
        return;
    }
    int bb = b - 4096;
    if (bb < 512) {
        int z = bb >> 6, t = bb & 63;
        int l = z >> 2, which = z & 3;
        const float* W = (which == 0 ? Wq : which == 1 ? Wk : which == 2 ? Wv : Wo) + (size_t)l * 65536;
        unsigned short* dst = (which < 3) ? qkvt + (size_t)l * 196608 + which * 65536
                                          : wot + (size_t)l * 65536;
        wt_tile(W, dst, 256, 256, (t & 7) * 32, (t >> 3) * 32, tid, tile);
    } else if (bb < 1024) {
        int b2 = bb - 512, l = b2 >> 8, t = b2 & 255;
        wt_tile(W1 + (size_t)l * D_MODEL * D_FF, w1t + (size_t)l * D_MODEL * D_FF,
                D_MODEL, D_FF, (t & 31) * 32, (t >> 5) * 32, tid, tile);
    } else if (bb < 1536) {
        int b3 = bb - 1024, l = b3 >> 8, t = b3 & 255;
        wt_tile(W2 + (size_t)l * D_FF * D_MODEL, w2t + (size_t)l * D_FF * D_MODEL,
                D_FF, D_MODEL, (t & 7) * 32, (t >> 3) * 32, tid, tile);
    } else if (bb < 1568) {
        int b4 = bb - 1536;
        wt_tile(W_emb, wembt, D_FEAT, D_MODEL, (b4 & 7) * 32, (b4 >> 3) * 32, tid, tile);
    } else if (bb < 1600) {
        int b5 = bb - 1568;
        wt_tile(W_out, woutt, D_MODEL, D_OUT, (b5 & 3) * 32, (b5 >> 2) * 32, tid, tile);
    } else {
        int i = (bb - 1600) * 256 + tid;
        if (i < NLAYER * 768) {
            int l = i / 768, j = i % 768;
            const float* src = j < 256 ? bq : j < 512 ? bk : bv;
            bqkv[i] = src[l * 256 + (j & 255)];
        }
    }
}

// ---------------- degree + edge histogram ----------------
__global__ void degree_hist_kernel(const int* __restrict__ ei,
                                   int* __restrict__ deg_out, int* __restrict__ deg_in,
                                   unsigned* __restrict__ hist) {
    int e = blockIdx.x * 256 + threadIdx.x;
    if (e < NEDGE) {
        int src = ei[e], dst = ei[NEDGE + e];
        atomicAdd(&deg_out[src], 1);
        atomicAdd(&deg_in[dst], 1);
        atomicAdd(&hist[(src >> 6) * 2048 + dst], 1);
    }
}

// ---------------- single-kernel slab allocator (per-64-key-group slabs) ----------------
__global__ void edge_alloc_kernel(const unsigned* __restrict__ hist,
                                  unsigned* __restrict__ offsets, unsigned* __restrict__ cursor,
                                  unsigned* __restrict__ gend, unsigned* __restrict__ gcursor) {
    int g = blockIdx.x;
    int t = threadIdx.x;
    unsigned v = hist[g * 64 + t];
    unsigned inc = v;
    #pragma unroll
    for (int off = 1; off < 64; off <<= 1) {
        unsigned u = __shfl_up(inc, off);
        if (t >= off) inc += u;
    }
    unsigned total = __shfl(inc, 63);
    unsigned base = 0;
    if (t == 63) base = atomicAdd(gcursor, total);
    base = __shfl(base, 63);
    unsigned o = base + inc - v;
    offsets[g * 64 + t] = o;
    cursor[g * 64 + t] = o;
    if (t == 63) gend[g] = base + total;
}

__global__ void edge_scatter_kernel(const int* __restrict__ ei, const int* __restrict__ etypes,
                                    unsigned* __restrict__ cursor, unsigned* __restrict__ packed) {
    int e = blockIdx.x * 256 + threadIdx.x;
    if (e < NEDGE) {
        int src = ei[e], dst = ei[NEDGE + e];
        int key = (src >> 6) * 2048 + dst;
        unsigned pos = atomicAdd(&cursor[key], 1);
        packed[pos] = (unsigned)dst | ((unsigned)(src & 63) << 11) | ((unsigned)etypes[e] << 17);
    }
}

// ---------------- fused centrality + layernorm1 ----------------
__global__ void centrality_ln_kernel(float* __restrict__ h,
                                     const float* __restrict__ din_l,
                                     const float* __restrict__ dout_l,
                                     const int* __restrict__ deg_in,
                                     const int* __restrict__ deg_out,
                                     const float* __restrict__ g,
                                     const float* __restrict__ b,
                                     unsigned short* __restrict__ y) {
    int row = blockIdx.x;
    int tid = threadIdx.x;
    int di = min(max(deg_in[row], 0), MAXDEG);
    int dn = min(max(deg_out[row], 0), MAXDEG);
    float v = h[row * D_MODEL + tid] + din_l[di * D_MODEL + tid] + dout_l[dn * D_MODEL + tid];
    h[row * D_MODEL + tid] = v;
    __shared__ float red[256];
    red[tid] = v; __syncthreads();
    for (int s = 128; s > 0; s >>= 1) { if (tid < s) red[tid] += red[tid + s]; __syncthreads(); }
    float mu = red[0] * (1.0f / D_MODEL);
    __syncthreads();
    float d = v - mu;
    red[tid] = d * d; __syncthreads();
    for (int s = 128; s > 0; s >>= 1) { if (tid < s) red[tid] += red[tid + s]; __syncthreads(); }
    float rstd = rsqrtf(red[0] * (1.0f / D_MODEL) + 1e-5f);
    y[row * D_MODEL + tid] = f2bf(d * rstd * g[tid] + b[tid]);
}

// ---------------- layernorm2 ----------------
__global__ void layernorm_kernel(const float* __restrict__ x,
                                 const float* __restrict__ g,
                                 const float* __restrict__ b,
                                 unsigned short* __restrict__ y) {
    int row = blockIdx.x;
    int tid = threadIdx.x;
    float v = x[row * D_MODEL + tid];
    __shared__ float red[256];
    red[tid] = v; __syncthreads();
    for (int s = 128; s > 0; s >>= 1) { if (tid < s) red[tid] += red[tid + s]; __syncthreads(); }
    float mu = red[0] * (1.0f / D_MODEL);
    __syncthreads();
    float d = v - mu;
    red[tid] = d * d; __syncthreads();
    for (int s = 128; s > 0; s >>= 1) { if (tid < s) red[tid] += red[tid + s]; __syncthreads(); }
    float rstd = rsqrtf(red[0] * (1.0f / D_MODEL) + 1e-5f);
    y[row * D_MODEL + tid] = f2bf(d * rstd * g[tid] + b[tid]);
}

// ---------------- bf16 MFMA GEMM, 32x64 tile, prefetched K-loop ----------------
template <int ACT, bool RESID, bool OUTBF16, bool AFP32>
__global__ void gemm_mfma_kernel(const void* __restrict__ Av,
                                 const unsigned short* __restrict__ Wt,
                                 const float* __restrict__ bias,
                                 float* __restrict__ C, unsigned short* __restrict__ Cb,
                                 int Nc, int K) {
    __shared__ __align__(16) unsigned short As[32][72];
    __shared__ __align__(16) unsigned short Bs[64][72];
    const unsigned short* A16 = (const unsigned short*)Av;
    const float* A32 = (const float*)Av;
    int tid = threadIdx.x;
    int m0 = blockIdx.y * 32, n0 = blockIdx.x * 64;
    int w = tid >> 6, lane = tid & 63;
    int rg = (w & 1) * 16, cg = (w >> 1) * 32;
    int m = lane & 15, quad = lane >> 4;
    f32x4 acc[2] = {{0.f, 0.f, 0.f, 0.f}, {0.f, 0.f, 0.f, 0.f}};
    int ar = tid >> 3, ac = (tid & 7) * 8;
    uint4 ra; float4 fa0, fa1; uint4 rb0, rb1;
    if (AFP32) {
        fa0 = *(const float4*)&A32[(size_t)(m0 + ar) * K + ac];
        fa1 = *(const float4*)&A32[(size_t)(m0 + ar) * K + ac + 4];
    } else {
        ra = *(const uint4*)&A16[(size_t)(m0 + ar) * K + ac];
    }
    rb0 = *(const uint4*)&Wt[(size_t)(n0 + ar) * K + ac];
    rb1 = *(const uint4*)&Wt[(size_t)(n0 + 32 + ar) * K + ac];
    for (int k0 = 0; k0 < K; k0 += 64) {
        if (AFP32) {
            u16x4 t0 = {f2bf(fa0.x), f2bf(fa0.y), f2bf(fa0.z), f2bf(fa0.w)};
            u16x4 t1 = {f2bf(fa1.x), f2bf(fa1.y), f2bf(fa1.z), f2bf(fa1.w)};
            *(u16x4*)&As[ar][ac] = t0;
            *(u16x4*)&As[ar][ac + 4] = t1;
        } else {
            *(uint4*)&As[ar][ac] = ra;
        }
        *(uint4*)&Bs[ar][ac] = rb0;
        *(uint4*)&Bs[ar + 32][ac] = rb1;
        __syncthreads();
        int kn = k0 + 64;
        if (kn < K) {
            if (AFP32) {
                fa0 = *(const float4*)&A32[(size_t)(m0 + ar) * K + kn + ac];
                fa1 = *(const float4*)&A32[(size_t)(m0 + ar) * K + kn + ac + 4];
            } else {
                ra = *(const uint4*)&A16[(size_t)(m0 + ar) * K + kn + ac];
            }
            rb0 = *(const uint4*)&Wt[(size_t)(n0 + ar) * K + kn + ac];
            rb1 = *(const uint4*)&Wt[(size_t)(n0 + 32 + ar) * K + kn + ac];
        }
        #pragma unroll
        for (int ks = 0; ks < 2; ks++) {
            short8 a = *(const short8*)&As[rg + m][ks * 32 + quad * 8];
            #pragma unroll
            for (int t = 0; t < 2; t++) {
                short8 b = *(const short8*)&Bs[cg + t * 16 + m][ks * 32 + quad * 8];
                acc[t] = __builtin_amdgcn_mfma_f32_16x16x32_bf16(a, b, acc[t], 0, 0, 0);
            }
        }
        __syncthreads();
    }
    #pragma unroll
    for (int t = 0; t < 2; t++) {
        #pragma unroll
        for (int reg = 0; reg < 4; reg++) {
            int row = m0 + rg + quad * 4 + reg;
            int col = n0 + cg + t * 16 + m;
            float val = acc[t][reg] + bias[col];
            if (ACT == 1) val = val * 0.5f * (1.0f + erff(val * 0.7071067811865476f));
            size_t idx = (size_t)row * Nc + col;
            if (RESID) val += C[idx];
            if (OUTBF16) Cb[idx] = f2bf(val);
            else C[idx] = val;
        }
    }
}

// ---------------- QKV GEMM: 32x64 tile (3 blocks/CU), Q/K -> qkvb; V-region (n0>=512)
// transposed through LDS and stored coalesced into vbt[dh][node] ----------------
__global__ void gemm_qkv_kernel(const unsigned short* __restrict__ A,
                                const unsigned short* __restrict__ Wt,
                                const float* __restrict__ bias,
                                unsigned short* __restrict__ Cb,
                                unsigned short* __restrict__ vbt) {
    const int K = D_MODEL, Nc = 768;
    __shared__ __align__(16) unsigned short As[32][72];
    __shared__ __align__(16) unsigned short Bs[64][72];
    int tid = threadIdx.x;
    int m0 = blockIdx.y * 32, n0 = blockIdx.x * 64;
    int w = tid >> 6, lane = tid & 63;
    int rg = (w & 1) * 16, cg = (w >> 1) * 32;
    int m = lane & 15, quad = lane >> 4;
    f32x4 acc[2] = {{0.f, 0.f, 0.f, 0.f}, {0.f, 0.f, 0.f, 0.f}};
    int ar = tid >> 3, ac = (tid & 7) * 8;
    uint4 ra = *(const uint4*)&A[(size_t)(m0 + ar) * K + ac];
    uint4 rb0 = *(const uint4*)&Wt[(size_t)(n0 + ar) * K + ac];
    uint4 rb1 = *(const uint4*)&Wt[(size_t)(n0 + 32 + ar) * K + ac];
    for (int k0 = 0; k0 < K; k0 += 64) {
        *(uint4*)&As[ar][ac] = ra;
        *(uint4*)&Bs[ar][ac] = rb0;
        *(uint4*)&Bs[ar + 32][ac] = rb1;
        __syncthreads();
        int kn = k0 + 64;
        if (kn < K) {
            ra = *(const uint4*)&A[(size_t)(m0 + ar) * K + kn + ac];
            rb0 = *(const uint4*)&Wt[(size_t)(n0 + ar) * K + kn + ac];
            rb1 = *(const uint4*)&Wt[(size_t)(n0 + 32 + ar) * K + kn + ac];
        }
        #pragma unroll
        for (int ks = 0; ks < 2; ks++) {
            short8 a = *(const short8*)&As[rg + m][ks * 32 + quad * 8];
            #pragma unroll
            for (int t = 0; t < 2; t++) {
                short8 b = *(const short8*)&Bs[cg + t * 16 + m][ks * 32 + quad * 8];
                acc[t] = __builtin_amdgcn_mfma_f32_16x16x32_bf16(a, b, acc[t], 0, 0, 0);
            }
        }
        __syncthreads();
    }
    if (n0 >= 512) {
        // V region: transpose through Bs (free after final barrier), coalesced store to vbt
        #pragma unroll
        for (int t = 0; t < 2; t++) {
            int cl = cg + t * 16 + m;                   // local col = V dim within tile
            float bcol = bias[n0 + cl];
            u16x4 tv;
            #pragma unroll
            for (int reg = 0; reg < 4; reg++) tv[reg] = f2bf(acc[t][reg] + bcol);
            *(u16x4*)&Bs[cl][rg + quad * 4] = tv;       // Bs[local col][local row]
        }
        __syncthreads();
        int rr = tid >> 2, cc = (tid & 3) * 8;
        uint4 o0 = *(const uint4*)&Bs[rr][cc];
        *(uint4*)&vbt[(size_t)(n0 - 512 + rr) * N_NODES + m0 + cc] = o0;
        return;
    }
    #pragma unroll
    for (int t = 0; t < 2; t++) {
        #pragma unroll
        for (int reg = 0; reg < 4; reg++) {
            int row = m0 + rg + quad * 4 + reg;
            int col = n0 + cg + t * 16 + m;
            Cb[(size_t)row * Nc + col] = f2bf(acc[t][reg] + bias[col]);
        }
    }
}

// ---------------- O-proj GEMM with in-staging merge: h += (ΣO/Σl) @ Wo + bo ----------------
__global__ void gemm_oproj_kernel(const float* __restrict__ part_O,
                                  const float* __restrict__ l_part,
                                  const unsigned short* __restrict__ Wt,
                                  const float* __restrict__ bias,
                                  float* __restrict__ C) {
    __shared__ __align__(16) unsigned short As[32][72];
    __shared__ __align__(16) unsigned short Bs[64][72];
    int tid = threadIdx.x;
    int m0 = blockIdx.y * 32, n0 = blockIdx.x * 64;
    int w = tid >> 6, lane = tid & 63;
    int rg = (w & 1) * 16, cg = (w >> 1) * 32;
    int m = lane & 15, quad = lane >> 4;
    f32x4 acc[2] = {{0.f, 0.f, 0.f, 0.f}, {0.f, 0.f, 0.f, 0.f}};
    int ar = tid >> 3, ac = (tid & 7) * 8;
    int row = m0 + ar;
    for (int k0 = 0; k0 < D_MODEL; k0 += 64) {
        int col = k0 + ac;
        int hh = col >> 5;
        float L = 0.f;
        float o[8] = {0.f, 0.f, 0.f, 0.f, 0.f, 0.f, 0.f, 0.f};
        #pragma unroll
        for (int js = 0; js < JSPLIT; js++) {
            L += l_part[((size_t)js * NHEAD + hh) * N_NODES + row];
            const float* pp = &part_O[((size_t)js * N_NODES + row) * D_MODEL + col];
            float4 p0 = *(const float4*)pp;
            float4 p1 = *(const float4*)(pp + 4);
            o[0] += p0.x; o[1] += p0.y; o[2] += p0.z; o[3] += p0.w;
            o[4] += p1.x; o[5] += p1.y; o[6] += p1.z; o[7] += p1.w;
        }
        float inv = 1.0f / L;
        u16x4 t0, t1;
        #pragma unroll
        for (int j = 0; j < 4; j++) { t0[j] = f2bf(o[j] * inv); t1[j] = f2bf(o[j + 4] * inv); }
        *(u16x4*)&As[ar][ac] = t0;
        *(u16x4*)&As[ar][ac + 4] = t1;
        *(uint4*)&Bs[ar][ac] = *(const uint4*)&Wt[(size_t)(n0 + ar) * D_MODEL + k0 + ac];
        *(uint4*)&Bs[ar + 32][ac] = *(const uint4*)&Wt[(size_t)(n0 + 32 + ar) * D_MODEL + k0 + ac];
        __syncthreads();
        #pragma unroll
        for (int ks = 0; ks < 2; ks++) {
            short8 a = *(const short8*)&As[rg + m][ks * 32 + quad * 8];
            #pragma unroll
            for (int t = 0; t < 2; t++) {
                short8 b = *(const short8*)&Bs[cg + t * 16 + m][ks * 32 + quad * 8];
                acc[t] = __builtin_amdgcn_mfma_f32_16x16x32_bf16(a, b, acc[t], 0, 0, 0);
            }
        }
        __syncthreads();
    }
    #pragma unroll
    for (int t = 0; t < 2; t++) {
        #pragma unroll
        for (int reg = 0; reg < 4; reg++) {
            int orow = m0 + rg + quad * 4 + reg;
            int ocol = n0 + cg + t * 16 + m;
            size_t idx = (size_t)orow * D_MODEL + ocol;
            C[idx] += acc[t][reg] + bias[ocol];
        }
    }
}

// ---------------- flash attention v5: swapped QK^T, NO xor swizzle ----------------
// ov row stride = 68 floats == 4 banks mod 32, so fixed-column accesses across rows r0+m are
// a natural 2-way alias (free, m136). v4's xor swizzle broke this (4-way) — removed.
// mfma(K, Q) puts P[q=r0+m][k] lane-local: bias reads f32x4, P packed to bf16 dwords in own
// ov row, read back as the exact PV A-fragment. 2 barriers/tile; K/V double-buffered.
// grid (N/64, H, JSPLIT), block 256 = 4 waves; wave w owns rows w*16..+16.
__global__ __launch_bounds__(256)
void flash_attn_kernel(const unsigned short* __restrict__ qkvb,
                       const unsigned short* __restrict__ vbt,
                       const unsigned char* __restrict__ bucket,
                       const float* __restrict__ spd_l,
                       const float* __restrict__ et_l,
                       const unsigned* __restrict__ offsets,
                       const unsigned* __restrict__ gend,
                       const unsigned* __restrict__ packed,
                       float* __restrict__ part_O,
                       float* __restrict__ l_part) {
    __shared__ __align__(16) unsigned short ks[2][64][40];
    __shared__ __align__(16) unsigned short vs[2][32][72];
    __shared__ __align__(16) float ov[64][68];
    __shared__ float et[8];

    int tid = threadIdx.x;
    int rb = blockIdx.x;
    int i0 = rb * 64;
    int hh = blockIdx.y;
    int js = blockIdx.z;
    int lane = tid & 63;
    if (tid < 8) et[tid] = et_l[tid * NHEAD + hh];
    float spd_reg = spd_l[(lane < 11 ? lane : 10) * NHEAD + hh];

    int w = tid >> 6;
    int m = lane & 15, quad = lane >> 4;
    int r0 = w * 16;
    short8 aq = *(const short8*)&qkvb[(size_t)(i0 + r0 + m) * 768 + hh * DH + quad * 8];
    float l_acc = 0.f;
    f32x4 oacc[2] = {{0.f, 0.f, 0.f, 0.f}, {0.f, 0.f, 0.f, 0.f}};
    const float scale = 0.17677669529663687f;
    const int NT = N_NODES / JSPLIT / 64;

    int krow = tid >> 2, kcol = (tid & 3) * 8;
    int vrow = tid >> 3, vcol = (tid & 7) * 8;
    int erow = r0 + (lane >> 2);          // wave-private SPD expand: own 16 rows
    int ecol = (lane & 3) * 16;

    int jbase = js * (N_NODES / JSPLIT);
    // tile 0: load + stage + expand (own rows)
    uint4 kpre = *(const uint4*)&qkvb[(size_t)(jbase + krow) * 768 + 256 + hh * DH + kcol];
    uint4 vpre = *(const uint4*)&vbt[(size_t)(hh * DH + vrow) * N_NODES + jbase + vcol];
    uint4 bpre = *(const uint4*)&bucket[(size_t)(i0 + erow) * N_NODES + jbase + ecol];
    *(uint4*)&ks[0][krow][kcol] = kpre;
    *(uint4*)&vs[0][vrow][vcol] = vpre;
    {
        const unsigned char* bb = (const unsigned char*)&bpre;
        #pragma unroll
        for (int g = 0; g < 4; g++) {
            f32x4 st;
            #pragma unroll
            for (int i2 = 0; i2 < 4; i2++)
                st[i2] = __int_as_float(__builtin_amdgcn_ds_bpermute(
                    ((int)bb[g * 4 + i2]) << 2, __float_as_int(spd_reg)));
            *(f32x4*)&ov[erow][ecol + g * 4] = st;
        }
    }

    int buf = 0;
    for (int jt = 0; jt < NT; jt++) {
        int j0 = jbase + jt * 64;
        __syncthreads();                    // B1: staging + own-row expansion visible to all
        // ---- cross-wave phase: per-edge bias scatter-add ----
        {
            unsigned key0 = (unsigned)rb * 2048 + j0;
            unsigned start = offsets[key0], end = gend[key0 >> 6];
            for (unsigned i = start + tid; i < end; i += 256) {
                unsigned p = packed[i];
                atomicAdd(&ov[(p >> 11) & 63][(p & 2047) - j0], et[(p >> 17) & 7]);
            }
        }
        // prefetch next tile during the atomic phase
        if (jt + 1 < NT) {
            int jn = j0 + 64;
            kpre = *(const uint4*)&qkvb[(size_t)(jn + krow) * 768 + 256 + hh * DH + kcol];
            vpre = *(const uint4*)&vbt[(size_t)(hh * DH + vrow) * N_NODES + jn + vcol];
            bpre = *(const uint4*)&bucket[(size_t)(i0 + erow) * N_NODES + jn + ecol];
        }
        __syncthreads();                    // B2: atomics complete
        // ---- wave-private phase: swapped QK (P row lane-local), bias f32x4, exp ----
        float sv[4][4];
        #pragma unroll
        for (int t = 0; t < 4; t++) {
            short8 bk8 = *(const short8*)&ks[buf][t * 16 + m][quad * 8];
            f32x4 z = {0.f, 0.f, 0.f, 0.f};
            // swapped: A=K rows (16t+m), B=Q rows (r0+m): D[k=4quad+r][q=m]
            f32x4 sacc = __builtin_amdgcn_mfma_f32_16x16x32_bf16(bk8, aq, z, 0, 0, 0);
            f32x4 bv = *(const f32x4*)&ov[r0 + m][t * 16 + quad * 4];
            #pragma unroll
            for (int r = 0; r < 4; r++) {
                float pv = __expf(sacc[r] * scale + bv[r]);
                sv[t][r] = pv;
                l_acc += pv;
            }
        }
        // pack P to bf16 dwords into own ov row (bias already consumed)
        unsigned* ovrow = (unsigned*)&ov[r0 + m][0];
        #pragma unroll
        for (int t = 0; t < 4; t++) {
            #pragma unroll
            for (int rp = 0; rp < 2; rp++) {
                unsigned d = (unsigned)f2bf(sv[t][2 * rp]) |
                             ((unsigned)f2bf(sv[t][2 * rp + 1]) << 16);
                ovrow[8 * t + 2 * quad + rp] = d;
            }
        }
        __builtin_amdgcn_s_waitcnt(0xC07F);   // lgkmcnt(0): own-row pack writes complete
        #pragma unroll
        for (int kh = 0; kh < 2; kh++) {
            uint4 pd = *(const uint4*)&ovrow[16 * kh + 4 * quad];
            short8 pa = *(short8*)&pd;
            #pragma unroll
            for (int t = 0; t < 2; t++) {
                short8 vb = *(const short8*)&vs[buf][t * 16 + m][kh * 32 + quad * 8];
                oacc[t] = __builtin_amdgcn_mfma_f32_16x16x32_bf16(pa, vb, oacc[t], 0, 0, 0);
            }
        }
        // stage next tile + expand next SPD into own ov rows (overwrites P remnants).
        // Safe without a barrier: ks/vs -> buf^1 (no current readers); ov writes touch only
        // OWN rows whose last readers (this wave's P b128 reads) already completed in-order.
        if (jt + 1 < NT) {
            *(uint4*)&ks[buf ^ 1][krow][kcol] = kpre;
            *(uint4*)&vs[buf ^ 1][vrow][vcol] = vpre;
            const unsigned char* bb = (const unsigned char*)&bpre;
            #pragma unroll
            for (int g = 0; g < 4; g++) {
                f32x4 st;
                #pragma unroll
                for (int i2 = 0; i2 < 4; i2++)
                    st[i2] = __int_as_float(__builtin_amdgcn_ds_bpermute(
                        ((int)bb[g * 4 + i2]) << 2, __float_as_int(spd_reg)));
                *(f32x4*)&ov[erow][ecol + g * 4] = st;
            }
            buf ^= 1;
        }
    }
    #pragma unroll
    for (int t = 0; t < 2; t++)
        #pragma unroll
        for (int r = 0; r < 4; r++)
            part_O[((size_t)js * N_NODES + i0 + r0 + quad * 4 + r) * D_MODEL + hh * DH + t * 16 + m] =
                oacc[t][r];
    // l reduction: lanes {m, m+16, m+32, m+48} hold partials for q-row r0+m
    l_acc += __int_as_float(__builtin_amdgcn_ds_bpermute((lane ^ 16) << 2, __float_as_int(l_acc)));
    l_acc += __int_as_float(__builtin_amdgcn_ds_bpermute((lane ^ 32) << 2, __float_as_int(l_acc)));
    if (quad == 0)
        l_part[((size_t)js * NHEAD + hh) * N_NODES + i0 + r0 + m] = l_acc;
}

// 256-byte-aligned workspace allocation
#define WS_ALLOC(type, name, count) \
    type* name = (type*)base; base += (((size_t)(count) * sizeof(type)) + 255) & ~(size_t)255;

extern "C" void kernel_launch(void* const* d_in, const int* in_sizes, int n_in,
                              void* d_out, int out_size, void* d_ws, size_t ws_size,
                              hipStream_t stream) {
    const float* x          = (const float*)d_in[0];
    const int*   edge_index = (const int*)d_in[1];
    const int*   edge_types = (const int*)d_in[2];
    const float* pos        = (const float*)d_in[3];
    const float* W_emb      = (const float*)d_in[4];
    const float* b_emb      = (const float*)d_in[5];
    const float* Wq         = (const float*)d_in[6];
    const float* Wk         = (const float*)d_in[7];
    const float* Wv         = (const float*)d_in[8];
    const float* Wo         = (const float*)d_in[9];
    const float* bq         = (const float*)d_in[10];
    const float* bk         = (const float*)d_in[11];
    const float* bv         = (const float*)d_in[12];
    const float* bo         = (const float*)d_in[13];
    const float* spd_table  = (const float*)d_in[14];
    const float* edge_table = (const float*)d_in[15];
    const float* din_emb    = (const float*)d_in[16];
    const float* dout_emb   = (const float*)d_in[17];
    const float* ln1_g      = (const float*)d_in[18];
    const float* ln1_b      = (const float*)d_in[19];
    const float* ln2_g      = (const float*)d_in[20];
    const float* ln2_b      = (const float*)d_in[21];
    const float* W1         = (const float*)d_in[22];
    const float* b1         = (const float*)d_in[23];
    const float* W2         = (const float*)d_in[24];
    const float* b2         = (const float*)d_in[25];
    const float* W_out      = (const float*)d_in[26];
    const float* b_out      = (const float*)d_in[27];
    float* out = (float*)d_out;

    char* base = (char*)d_ws;
    WS_ALLOC(int, deg_out, N_NODES)
    WS_ALLOC(int, deg_in, N_NODES)
    WS_ALLOC(float, h, N_NODES * D_MODEL)
    WS_ALLOC(unsigned short, xb, N_NODES * D_MODEL)
    WS_ALLOC(unsigned short, qkvb, N_NODES * 768)
    WS_ALLOC(unsigned short, vbt, D_MODEL * N_NODES)
    WS_ALLOC(unsigned short, ffnb, N_NODES * D_FF)
    WS_ALLOC(unsigned char, bucket, (size_t)N_NODES * N_NODES)
    WS_ALLOC(unsigned short, qkvt, NLAYER * 768 * D_MODEL)
    WS_ALLOC(unsigned short, wot, NLAYER * D_MODEL * D_MODEL)
    WS_ALLOC(unsigned short, w1t, NLAYER * D_MODEL * D_FF)
    WS_ALLOC(unsigned short, w2t, NLAYER * D_FF * D_MODEL)
    WS_ALLOC(unsigned short, wembt, D_FEAT * D_MODEL)
    WS_ALLOC(unsigned short, woutt, D_MODEL * D_OUT)
    WS_ALLOC(float, bqkv, NLAYER * 768)
    WS_ALLOC(unsigned, hist, 65536)
    WS_ALLOC(unsigned, offsets, 65536)
    WS_ALLOC(unsigned, cursor, 65536)
    WS_ALLOC(unsigned, gend, 1024)
    WS_ALLOC(unsigned, gcursor, 1)
    WS_ALLOC(unsigned, packed, NEDGE)
    WS_ALLOC(float, part_O, (size_t)JSPLIT * N_NODES * D_MODEL)
    WS_ALLOC(float, l_part, (size_t)JSPLIT * NHEAD * N_NODES)

    // ---- prep ----
    mega_prep_kernel<<<5702, 256, 0, stream>>>(pos, bucket, hist, deg_out, deg_in, gcursor,
                                               Wq, Wk, Wv, Wo, W1, W2, W_emb, W_out,
                                               bq, bk, bv, qkvt, wot, w1t, w2t, wembt, woutt, bqkv);
    degree_hist_kernel<<<NEDGE / 256, 256, 0, stream>>>(edge_index, deg_out, deg_in, hist);
    edge_alloc_kernel<<<1024, 64, 0, stream>>>(hist, offsets, cursor, gend, gcursor);
    edge_scatter_kernel<<<NEDGE / 256, 256, 0, stream>>>(edge_index, edge_types, cursor, packed);

    // embed: h = x @ W_emb + b_emb (fp32 A, cast in staging)
    gemm_mfma_kernel<0, false, false, true><<<dim3(D_MODEL / 64, N_NODES / 32), 256, 0, stream>>>(
        x, wembt, b_emb, h, nullptr, D_MODEL, D_FEAT);

    for (int l = 0; l < NLAYER; l++) {
        centrality_ln_kernel<<<N_NODES, 256, 0, stream>>>(
            h, din_emb + (size_t)l * (MAXDEG + 1) * D_MODEL,
            dout_emb + (size_t)l * (MAXDEG + 1) * D_MODEL, deg_in, deg_out,
            ln1_g + l * D_MODEL, ln1_b + l * D_MODEL, xb);

        // QKV gemm, 32x64 tile (768 blocks = 3/CU); V-region -> vbt via LDS transpose
        gemm_qkv_kernel<<<dim3(768 / 64, N_NODES / 32), 256, 0, stream>>>(
            xb, qkvt + (size_t)l * 768 * D_MODEL, bqkv + l * 768, qkvb, vbt);

        flash_attn_kernel<<<dim3(N_NODES / 64, NHEAD, JSPLIT), 256, 0, stream>>>(
            qkvb, vbt, bucket, spd_table + (size_t)l * 11 * NHEAD,
            edge_table + (size_t)l * 8 * NHEAD, offsets, gend, packed, part_O, l_part);

        gemm_oproj_kernel<<<dim3(D_MODEL / 64, N_NODES / 32), 256, 0, stream>>>(
            part_O, l_part, wot + (size_t)l * D_MODEL * D_MODEL, bo + l * D_MODEL, h);

        layernorm_kernel<<<N_NODES, 256, 0, stream>>>(h, ln2_g + l * D_MODEL, ln2_b + l * D_MODEL, xb);

        // FFN1, 32x64 tile (1024 blocks = 4/CU), GELU, bf16 out
        gemm_mfma_kernel<1, false, true, false><<<dim3(D_FF / 64, N_NODES / 32), 256, 0, stream>>>(
            xb, w1t + (size_t)l * D_MODEL * D_FF, b1 + l * D_FF, nullptr, ffnb, D_FF, D_MODEL);

        gemm_mfma_kernel<0, true, false, false><<<dim3(D_MODEL / 64, N_NODES / 32), 256, 0, stream>>>(
            ffnb, w2t + (size_t)l * D_FF * D_MODEL, b2 + l * D_MODEL, h, nullptr, D_MODEL, D_FF);
    }

    // final: out = h @ W_out + b_out (fp32 A, cast in staging)
    gemm_mfma_kernel<0, false, false, true><<<dim3(D_OUT / 64, N_NODES / 32), 256, 0, stream>>>(
        h, woutt, b_out, out, nullptr, D_OUT, D_MODEL);
}

// Round 12
// 291.871 us; speedup vs baseline: 1.0870x; 1.0129x over previous
//
#include <hip/hip_runtime.h>
#include <math.h>

#define N_NODES 2048
#define D_MODEL 256
#define D_FEAT 128
#define NHEAD 8
#define DH 32
#define NLAYER 2
#define NEDGE 65536
#define D_FF 1024
#define D_OUT 128
#define MAXDEG 512
#define JSPLIT 4

typedef __attribute__((ext_vector_type(8))) short short8;
typedef __attribute__((ext_vector_type(4))) float f32x4;
typedef __attribute__((ext_vector_type(4))) unsigned short u16x4;

__device__ __forceinline__ unsigned short f2bf(float f) {
    unsigned u = __float_as_uint(f);
    unsigned r = (u + 0x7FFFu + ((u >> 16) & 1u)) >> 16;
    return (unsigned short)r;
}

// ---------------- mega prep: bucket table + zeroing + all weight transposes ----------------
__device__ __forceinline__ void wt_tile(const float* __restrict__ W, unsigned short* __restrict__ Wt,
                                        int K, int Nc, int n0, int k0, int tid,
                                        unsigned short (*tile)[33]) {
    int r = tid >> 3, cg = (tid & 7) * 4;
    float4 w4 = *(const float4*)&W[(size_t)(k0 + r) * Nc + n0 + cg];
    tile[r][cg + 0] = f2bf(w4.x); tile[r][cg + 1] = f2bf(w4.y);
    tile[r][cg + 2] = f2bf(w4.z); tile[r][cg + 3] = f2bf(w4.w);
    __syncthreads();
    int c = tid >> 3, rg = (tid & 7) * 4;
    u16x4 o;
    #pragma unroll
    for (int j = 0; j < 4; j++) o[j] = tile[rg + j][c];
    *(u16x4*)&Wt[(size_t)(n0 + c) * K + k0 + rg] = o;
}

__global__ void mega_prep_kernel(const float* __restrict__ pos, unsigned char* __restrict__ bucket,
                                 unsigned* __restrict__ hist, int* __restrict__ deg_out,
                                 int* __restrict__ deg_in, unsigned* __restrict__ gcursor,
                                 const float* __restrict__ Wq, const float* __restrict__ Wk,
                                 const float* __restrict__ Wv, const float* __restrict__ Wo,
                                 const float* __restrict__ W1, const float* __restrict__ W2,
                                 const float* __restrict__ W_emb, const float* __restrict__ W_out,
                                 const float* __restrict__ bq, const float* __restrict__ bk,
                                 const float* __restrict__ bv,
                                 unsigned short* __restrict__ qkvt, unsigned short* __restrict__ wot,
                                 unsigned short* __restrict__ w1t, unsigned short* __restrict__ w2t,
                                 unsigned short* __restrict__ wembt, unsigned short* __restrict__ woutt,
                                 float* __restrict__ bqkv) {
    __shared__ unsigned short tile[32][33];
    int b = blockIdx.x, tid = threadIdx.x;
    if (b < 4096) {
        int i = b * 256 + tid;
        float4 p = *(const float4*)&pos[(size_t)i * 4];
        unsigned b0 = (unsigned)fminf(fmaxf(p.x * 10.f + 0.5f, 0.f), 10.f);
        unsigned b1 = (unsigned)fminf(fmaxf(p.y * 10.f + 0.5f, 0.f), 10.f);
        unsigned b2 = (unsigned)fminf(fmaxf(p.z * 10.f + 0.5f, 0.f), 10.f);
        unsigned b3 = (unsigned)fminf(fmaxf(p.w * 10.f + 0.5f, 0.f), 10.f);
        ((unsigned*)bucket)[i] = b0 | (b1 << 8) | (b2 << 16) | (b3 << 24);
        if (b < 64) {
            #pragma unroll
            for (int k = 0; k < 4; k++) hist[b * 1024 + k * 256 + tid] = 0;
        } else if (b == 64) {
            #pragma unroll
            for (int k = 0; k < 8; k++) deg_out[k * 256 + tid] = 0;
            #pragma unroll
            for (int k = 0; k < 8; k++) deg_in[k * 256 + tid] = 0;
            if (tid == 0) *gcursor = 0;
        }
        return;
    }
    int bb = b - 4096;
    if (bb < 512) {
        int z = bb >> 6, t = bb & 63;
        int l = z >> 2, which = z & 3;
        const float* W = (which == 0 ? Wq : which == 1 ? Wk : which == 2 ? Wv : Wo) + (size_t)l * 65536;
        unsigned short* dst = (which < 3) ? qkvt + (size_t)l * 196608 + which * 65536
                                          : wot + (size_t)l * 65536;
        wt_tile(W, dst, 256, 256, (t & 7) * 32, (t >> 3) * 32, tid, tile);
    } else if (bb < 1024) {
        int b2 = bb - 512, l = b2 >> 8, t = b2 & 255;
        wt_tile(W1 + (size_t)l * D_MODEL * D_FF, w1t + (size_t)l * D_MODEL * D_FF,
                D_MODEL, D_FF, (t & 31) * 32, (t >> 5) * 32, tid, tile);
    } else if (bb < 1536) {
        int b3 = bb - 1024, l = b3 >> 8, t = b3 & 255;
        wt_tile(W2 + (size_t)l * D_FF * D_MODEL, w2t + (size_t)l * D_FF * D_MODEL,
                D_FF, D_MODEL, (t & 7) * 32, (t >> 3) * 32, tid, tile);
    } else if (bb < 1568) {
        int b4 = bb - 1536;
        wt_tile(W_emb, wembt, D_FEAT, D_MODEL, (b4 & 7) * 32, (b4 >> 3) * 32, tid, tile);
    } else if (bb < 1600) {
        int b5 = bb - 1568;
        wt_tile(W_out, woutt, D_MODEL, D_OUT, (b5 & 3) * 32, (b5 >> 2) * 32, tid, tile);
    } else {
        int i = (bb - 1600) * 256 + tid;
        if (i < NLAYER * 768) {
            int l = i / 768, j = i % 768;
            const float* src = j < 256 ? bq : j < 512 ? bk : bv;
            bqkv[i] = src[l * 256 + (j & 255)];
        }
    }
}

// ---------------- degree + edge histogram ----------------
__global__ void degree_hist_kernel(const int* __restrict__ ei,
                                   int* __restrict__ deg_out, int* __restrict__ deg_in,
                                   unsigned* __restrict__ hist) {
    int e = blockIdx.x * 256 + threadIdx.x;
    if (e < NEDGE) {
        int src = ei[e], dst = ei[NEDGE + e];
        atomicAdd(&deg_out[src], 1);
        atomicAdd(&deg_in[dst], 1);
        atomicAdd(&hist[(src >> 6) * 2048 + dst], 1);
    }
}

// ---------------- single-kernel slab allocator (per-64-key-group slabs) ----------------
__global__ void edge_alloc_kernel(const unsigned* __restrict__ hist,
                                  unsigned* __restrict__ offsets, unsigned* __restrict__ cursor,
                                  unsigned* __restrict__ gend, unsigned* __restrict__ gcursor) {
    int g = blockIdx.x;
    int t = threadIdx.x;
    unsigned v = hist[g * 64 + t];
    unsigned inc = v;
    #pragma unroll
    for (int off = 1; off < 64; off <<= 1) {
        unsigned u = __shfl_up(inc, off);
        if (t >= off) inc += u;
    }
    unsigned total = __shfl(inc, 63);
    unsigned base = 0;
    if (t == 63) base = atomicAdd(gcursor, total);
    base = __shfl(base, 63);
    unsigned o = base + inc - v;
    offsets[g * 64 + t] = o;
    cursor[g * 64 + t] = o;
    if (t == 63) gend[g] = base + total;
}

__global__ void edge_scatter_kernel(const int* __restrict__ ei, const int* __restrict__ etypes,
                                    unsigned* __restrict__ cursor, unsigned* __restrict__ packed) {
    int e = blockIdx.x * 256 + threadIdx.x;
    if (e < NEDGE) {
        int src = ei[e], dst = ei[NEDGE + e];
        int key = (src >> 6) * 2048 + dst;
        unsigned pos = atomicAdd(&cursor[key], 1);
        packed[pos] = (unsigned)dst | ((unsigned)(src & 63) << 11) | ((unsigned)etypes[e] << 17);
    }
}

// ---------------- fused centrality + layernorm1 ----------------
__global__ void centrality_ln_kernel(float* __restrict__ h,
                                     const float* __restrict__ din_l,
                                     const float* __restrict__ dout_l,
                                     const int* __restrict__ deg_in,
                                     const int* __restrict__ deg_out,
                                     const float* __restrict__ g,
                                     const float* __restrict__ b,
                                     unsigned short* __restrict__ y) {
    int row = blockIdx.x;
    int tid = threadIdx.x;
    int di = min(max(deg_in[row], 0), MAXDEG);
    int dn = min(max(deg_out[row], 0), MAXDEG);
    float v = h[row * D_MODEL + tid] + din_l[di * D_MODEL + tid] + dout_l[dn * D_MODEL + tid];
    h[row * D_MODEL + tid] = v;
    __shared__ float red[256];
    red[tid] = v; __syncthreads();
    for (int s = 128; s > 0; s >>= 1) { if (tid < s) red[tid] += red[tid + s]; __syncthreads(); }
    float mu = red[0] * (1.0f / D_MODEL);
    __syncthreads();
    float d = v - mu;
    red[tid] = d * d; __syncthreads();
    for (int s = 128; s > 0; s >>= 1) { if (tid < s) red[tid] += red[tid + s]; __syncthreads(); }
    float rstd = rsqrtf(red[0] * (1.0f / D_MODEL) + 1e-5f);
    y[row * D_MODEL + tid] = f2bf(d * rstd * g[tid] + b[tid]);
}

// ---------------- layernorm2 ----------------
__global__ void layernorm_kernel(const float* __restrict__ x,
                                 const float* __restrict__ g,
                                 const float* __restrict__ b,
                                 unsigned short* __restrict__ y) {
    int row = blockIdx.x;
    int tid = threadIdx.x;
    float v = x[row * D_MODEL + tid];
    __shared__ float red[256];
    red[tid] = v; __syncthreads();
    for (int s = 128; s > 0; s >>= 1) { if (tid < s) red[tid] += red[tid + s]; __syncthreads(); }
    float mu = red[0] * (1.0f / D_MODEL);
    __syncthreads();
    float d = v - mu;
    red[tid] = d * d; __syncthreads();
    for (int s = 128; s > 0; s >>= 1) { if (tid < s) red[tid] += red[tid + s]; __syncthreads(); }
    float rstd = rsqrtf(red[0] * (1.0f / D_MODEL) + 1e-5f);
    y[row * D_MODEL + tid] = f2bf(d * rstd * g[tid] + b[tid]);
}

// ---------------- bf16 MFMA GEMM, 32x64 tile, SINGLE-SHOT K staging ----------------
// Stage the full KSTEP extent once -> ONE barrier -> all MFMAs back-to-back -> epilogue.
// K <= 256 ops run with K == KSTEP (1 barrier/block vs 8 in the old 64-step loop);
// FFN2 (K=1024) loops 4x KSTEP=256 (7 barriers vs 32). LDS stride 264 == 4 banks mod 32:
// same free 2-way alias profile as the proven [72] layout.
template <int KSTEP, int ACT, bool RESID, bool OUTBF16, bool AFP32>
__global__ void gemm_ss_kernel(const void* __restrict__ Av,
                               const unsigned short* __restrict__ Wt,
                               const float* __restrict__ bias,
                               float* __restrict__ C, unsigned short* __restrict__ Cb,
                               int Nc, int K) {
    __shared__ __align__(16) unsigned short As[32][KSTEP + 8];
    __shared__ __align__(16) unsigned short Bs[64][KSTEP + 8];
    const unsigned short* A16 = (const unsigned short*)Av;
    const float* A32 = (const float*)Av;
    int tid = threadIdx.x;
    int m0 = blockIdx.y * 32, n0 = blockIdx.x * 64;
    int w = tid >> 6, lane = tid & 63;
    int rg = (w & 1) * 16, cg = (w >> 1) * 32;
    int m = lane & 15, quad = lane >> 4;
    f32x4 acc[2] = {{0.f, 0.f, 0.f, 0.f}, {0.f, 0.f, 0.f, 0.f}};
    int ar = tid >> 3, ac8 = (tid & 7) * 8;
    for (int k0 = 0; k0 < K; k0 += KSTEP) {
        if (k0) __syncthreads();
        if (AFP32) {
            #pragma unroll
            for (int j = 0; j < KSTEP / 64; j++) {
                const float* ap = &A32[(size_t)(m0 + ar) * K + k0 + ac8 + j * 64];
                float4 f0 = *(const float4*)ap;
                float4 f1 = *(const float4*)(ap + 4);
                u16x4 t0 = {f2bf(f0.x), f2bf(f0.y), f2bf(f0.z), f2bf(f0.w)};
                u16x4 t1 = {f2bf(f1.x), f2bf(f1.y), f2bf(f1.z), f2bf(f1.w)};
                *(u16x4*)&As[ar][ac8 + j * 64] = t0;
                *(u16x4*)&As[ar][ac8 + j * 64 + 4] = t1;
            }
        } else {
            #pragma unroll
            for (int j = 0; j < KSTEP / 64; j++)
                *(uint4*)&As[ar][ac8 + j * 64] =
                    *(const uint4*)&A16[(size_t)(m0 + ar) * K + k0 + ac8 + j * 64];
        }
        #pragma unroll
        for (int j = 0; j < KSTEP / 64; j++) {
            *(uint4*)&Bs[ar][ac8 + j * 64] =
                *(const uint4*)&Wt[(size_t)(n0 + ar) * K + k0 + ac8 + j * 64];
            *(uint4*)&Bs[ar + 32][ac8 + j * 64] =
                *(const uint4*)&Wt[(size_t)(n0 + 32 + ar) * K + k0 + ac8 + j * 64];
        }
        __syncthreads();
        #pragma unroll
        for (int ks = 0; ks < KSTEP / 32; ks++) {
            short8 a = *(const short8*)&As[rg + m][ks * 32 + quad * 8];
            #pragma unroll
            for (int t = 0; t < 2; t++) {
                short8 b = *(const short8*)&Bs[cg + t * 16 + m][ks * 32 + quad * 8];
                acc[t] = __builtin_amdgcn_mfma_f32_16x16x32_bf16(a, b, acc[t], 0, 0, 0);
            }
        }
    }
    #pragma unroll
    for (int t = 0; t < 2; t++) {
        #pragma unroll
        for (int reg = 0; reg < 4; reg++) {
            int row = m0 + rg + quad * 4 + reg;
            int col = n0 + cg + t * 16 + m;
            float val = acc[t][reg] + bias[col];
            if (ACT == 1) val = val * 0.5f * (1.0f + erff(val * 0.7071067811865476f));
            size_t idx = (size_t)row * Nc + col;
            if (RESID) val += C[idx];
            if (OUTBF16) Cb[idx] = f2bf(val);
            else C[idx] = val;
        }
    }
}

// ---------------- QKV GEMM: single-shot K=256; Q/K -> qkvb; V-region (n0>=512)
// transposed through LDS and stored coalesced into vbt[dh][node] ----------------
__global__ void gemm_qkv_kernel(const unsigned short* __restrict__ A,
                                const unsigned short* __restrict__ Wt,
                                const float* __restrict__ bias,
                                unsigned short* __restrict__ Cb,
                                unsigned short* __restrict__ vbt) {
    const int K = D_MODEL, Nc = 768;
    __shared__ __align__(16) unsigned short As[32][264];
    __shared__ __align__(16) unsigned short Bs[64][264];
    int tid = threadIdx.x;
    int m0 = blockIdx.y * 32, n0 = blockIdx.x * 64;
    int w = tid >> 6, lane = tid & 63;
    int rg = (w & 1) * 16, cg = (w >> 1) * 32;
    int m = lane & 15, quad = lane >> 4;
    f32x4 acc[2] = {{0.f, 0.f, 0.f, 0.f}, {0.f, 0.f, 0.f, 0.f}};
    int ar = tid >> 3, ac8 = (tid & 7) * 8;
    #pragma unroll
    for (int j = 0; j < 4; j++)
        *(uint4*)&As[ar][ac8 + j * 64] =
            *(const uint4*)&A[(size_t)(m0 + ar) * K + ac8 + j * 64];
    #pragma unroll
    for (int j = 0; j < 4; j++) {
        *(uint4*)&Bs[ar][ac8 + j * 64] =
            *(const uint4*)&Wt[(size_t)(n0 + ar) * K + ac8 + j * 64];
        *(uint4*)&Bs[ar + 32][ac8 + j * 64] =
            *(const uint4*)&Wt[(size_t)(n0 + 32 + ar) * K + ac8 + j * 64];
    }
    __syncthreads();
    #pragma unroll
    for (int ks = 0; ks < 8; ks++) {
        short8 a = *(const short8*)&As[rg + m][ks * 32 + quad * 8];
        #pragma unroll
        for (int t = 0; t < 2; t++) {
            short8 b = *(const short8*)&Bs[cg + t * 16 + m][ks * 32 + quad * 8];
            acc[t] = __builtin_amdgcn_mfma_f32_16x16x32_bf16(a, b, acc[t], 0, 0, 0);
        }
    }
    if (n0 >= 512) {
        __syncthreads();   // all waves done reading Bs
        // V region: transpose through Bs, coalesced store to vbt
        #pragma unroll
        for (int t = 0; t < 2; t++) {
            int cl = cg + t * 16 + m;                   // local col = V dim within tile
            float bcol = bias[n0 + cl];
            u16x4 tv;
            #pragma unroll
            for (int reg = 0; reg < 4; reg++) tv[reg] = f2bf(acc[t][reg] + bcol);
            *(u16x4*)&Bs[cl][rg + quad * 4] = tv;       // Bs[local col][local row]
        }
        __syncthreads();
        int rr = tid >> 2, cc = (tid & 3) * 8;
        uint4 o0 = *(const uint4*)&Bs[rr][cc];
        *(uint4*)&vbt[(size_t)(n0 - 512 + rr) * N_NODES + m0 + cc] = o0;
        return;
    }
    #pragma unroll
    for (int t = 0; t < 2; t++) {
        #pragma unroll
        for (int reg = 0; reg < 4; reg++) {
            int row = m0 + rg + quad * 4 + reg;
            int col = n0 + cg + t * 16 + m;
            Cb[(size_t)row * Nc + col] = f2bf(acc[t][reg] + bias[col]);
        }
    }
}

// ---------------- O-proj GEMM, single-shot K=256, in-staging merge: h += (ΣO/Σl)@Wo + bo ----
__global__ void gemm_oproj_kernel(const float* __restrict__ part_O,
                                  const float* __restrict__ l_part,
                                  const unsigned short* __restrict__ Wt,
                                  const float* __restrict__ bias,
                                  float* __restrict__ C) {
    __shared__ __align__(16) unsigned short As[32][264];
    __shared__ __align__(16) unsigned short Bs[64][264];
    int tid = threadIdx.x;
    int m0 = blockIdx.y * 32, n0 = blockIdx.x * 64;
    int w = tid >> 6, lane = tid & 63;
    int rg = (w & 1) * 16, cg = (w >> 1) * 32;
    int m = lane & 15, quad = lane >> 4;
    f32x4 acc[2] = {{0.f, 0.f, 0.f, 0.f}, {0.f, 0.f, 0.f, 0.f}};
    int ar = tid >> 3, ac8 = (tid & 7) * 8;
    int row = m0 + ar;
    #pragma unroll
    for (int j = 0; j < 4; j++) {
        int col = ac8 + j * 64;
        int hh = col >> 5;
        float L = 0.f;
        float o[8] = {0.f, 0.f, 0.f, 0.f, 0.f, 0.f, 0.f, 0.f};
        #pragma unroll
        for (int js = 0; js < JSPLIT; js++) {
            L += l_part[((size_t)js * NHEAD + hh) * N_NODES + row];
            const float* pp = &part_O[((size_t)js * N_NODES + row) * D_MODEL + col];
            float4 p0 = *(const float4*)pp;
            float4 p1 = *(const float4*)(pp + 4);
            o[0] += p0.x; o[1] += p0.y; o[2] += p0.z; o[3] += p0.w;
            o[4] += p1.x; o[5] += p1.y; o[6] += p1.z; o[7] += p1.w;
        }
        float inv = 1.0f / L;
        u16x4 t0, t1;
        #pragma unroll
        for (int jj = 0; jj < 4; jj++) { t0[jj] = f2bf(o[jj] * inv); t1[jj] = f2bf(o[jj + 4] * inv); }
        *(u16x4*)&As[ar][col] = t0;
        *(u16x4*)&As[ar][col + 4] = t1;
    }
    #pragma unroll
    for (int j = 0; j < 4; j++) {
        *(uint4*)&Bs[ar][ac8 + j * 64] =
            *(const uint4*)&Wt[(size_t)(n0 + ar) * D_MODEL + ac8 + j * 64];
        *(uint4*)&Bs[ar + 32][ac8 + j * 64] =
            *(const uint4*)&Wt[(size_t)(n0 + 32 + ar) * D_MODEL + ac8 + j * 64];
    }
    __syncthreads();
    #pragma unroll
    for (int ks = 0; ks < 8; ks++) {
        short8 a = *(const short8*)&As[rg + m][ks * 32 + quad * 8];
        #pragma unroll
        for (int t = 0; t < 2; t++) {
            short8 b = *(const short8*)&Bs[cg + t * 16 + m][ks * 32 + quad * 8];
            acc[t] = __builtin_amdgcn_mfma_f32_16x16x32_bf16(a, b, acc[t], 0, 0, 0);
        }
    }
    #pragma unroll
    for (int t = 0; t < 2; t++) {
        #pragma unroll
        for (int reg = 0; reg < 4; reg++) {
            int orow = m0 + rg + quad * 4 + reg;
            int ocol = n0 + cg + t * 16 + m;
            size_t idx = (size_t)orow * D_MODEL + ocol;
            C[idx] += acc[t][reg] + bias[ocol];
        }
    }
}

// ---------------- flash attention v5: swapped QK^T, no swizzle (proven R11) ----------------
// grid (N/64, H, JSPLIT), block 256 = 4 waves; wave w owns rows w*16..+16.
__global__ __launch_bounds__(256)
void flash_attn_kernel(const unsigned short* __restrict__ qkvb,
                       const unsigned short* __restrict__ vbt,
                       const unsigned char* __restrict__ bucket,
                       const float* __restrict__ spd_l,
                       const float* __restrict__ et_l,
                       const unsigned* __restrict__ offsets,
                       const unsigned* __restrict__ gend,
                       const unsigned* __restrict__ packed,
                       float* __restrict__ part_O,
                       float* __restrict__ l_part) {
    __shared__ __align__(16) unsigned short ks[2][64][40];
    __shared__ __align__(16) unsigned short vs[2][32][72];
    __shared__ __align__(16) float ov[64][68];
    __shared__ float et[8];

    int tid = threadIdx.x;
    int rb = blockIdx.x;
    int i0 = rb * 64;
    int hh = blockIdx.y;
    int js = blockIdx.z;
    int lane = tid & 63;
    if (tid < 8) et[tid] = et_l[tid * NHEAD + hh];
    float spd_reg = spd_l[(lane < 11 ? lane : 10) * NHEAD + hh];

    int w = tid >> 6;
    int m = lane & 15, quad = lane >> 4;
    int r0 = w * 16;
    short8 aq = *(const short8*)&qkvb[(size_t)(i0 + r0 + m) * 768 + hh * DH + quad * 8];
    float l_acc = 0.f;
    f32x4 oacc[2] = {{0.f, 0.f, 0.f, 0.f}, {0.f, 0.f, 0.f, 0.f}};
    const float scale = 0.17677669529663687f;
    const int NT = N_NODES / JSPLIT / 64;

    int krow = tid >> 2, kcol = (tid & 3) * 8;
    int vrow = tid >> 3, vcol = (tid & 7) * 8;
    int erow = r0 + (lane >> 2);          // wave-private SPD expand: own 16 rows
    int ecol = (lane & 3) * 16;

    int jbase = js * (N_NODES / JSPLIT);
    // tile 0: load + stage + expand (own rows)
    uint4 kpre = *(const uint4*)&qkvb[(size_t)(jbase + krow) * 768 + 256 + hh * DH + kcol];
    uint4 vpre = *(const uint4*)&vbt[(size_t)(hh * DH + vrow) * N_NODES + jbase + vcol];
    uint4 bpre = *(const uint4*)&bucket[(size_t)(i0 + erow) * N_NODES + jbase + ecol];
    *(uint4*)&ks[0][krow][kcol] = kpre;
    *(uint4*)&vs[0][vrow][vcol] = vpre;
    {
        const unsigned char* bb = (const unsigned char*)&bpre;
        #pragma unroll
        for (int g = 0; g < 4; g++) {
            f32x4 st;
            #pragma unroll
            for (int i2 = 0; i2 < 4; i2++)
                st[i2] = __int_as_float(__builtin_amdgcn_ds_bpermute(
                    ((int)bb[g * 4 + i2]) << 2, __float_as_int(spd_reg)));
            *(f32x4*)&ov[erow][ecol + g * 4] = st;
        }
    }

    int buf = 0;
    for (int jt = 0; jt < NT; jt++) {
        int j0 = jbase + jt * 64;
        __syncthreads();                    // B1: staging + own-row expansion visible to all
        // ---- cross-wave phase: per-edge bias scatter-add ----
        {
            unsigned key0 = (unsigned)rb * 2048 + j0;
            unsigned start = offsets[key0], end = gend[key0 >> 6];
            for (unsigned i = start + tid; i < end; i += 256) {
                unsigned p = packed[i];
                atomicAdd(&ov[(p >> 11) & 63][(p & 2047) - j0], et[(p >> 17) & 7]);
            }
        }
        // prefetch next tile during the atomic phase
        if (jt + 1 < NT) {
            int jn = j0 + 64;
            kpre = *(const uint4*)&qkvb[(size_t)(jn + krow) * 768 + 256 + hh * DH + kcol];
            vpre = *(const uint4*)&vbt[(size_t)(hh * DH + vrow) * N_NODES + jn + vcol];
            bpre = *(const uint4*)&bucket[(size_t)(i0 + erow) * N_NODES + jn + ecol];
        }
        __syncthreads();                    // B2: atomics complete
        // ---- wave-private phase: swapped QK (P row lane-local), bias f32x4, exp ----
        float sv[4][4];
        #pragma unroll
        for (int t = 0; t < 4; t++) {
            short8 bk8 = *(const short8*)&ks[buf][t * 16 + m][quad * 8];
            f32x4 z = {0.f, 0.f, 0.f, 0.f};
            // swapped: A=K rows (16t+m), B=Q rows (r0+m): D[k=4quad+r][q=m]
            f32x4 sacc = __builtin_amdgcn_mfma_f32_16x16x32_bf16(bk8, aq, z, 0, 0, 0);
            f32x4 bv = *(const f32x4*)&ov[r0 + m][t * 16 + quad * 4];
            #pragma unroll
            for (int r = 0; r < 4; r++) {
                float pv = __expf(sacc[r] * scale + bv[r]);
                sv[t][r] = pv;
                l_acc += pv;
            }
        }
        // pack P to bf16 dwords into own ov row (bias already consumed)
        unsigned* ovrow = (unsigned*)&ov[r0 + m][0];
        #pragma unroll
        for (int t = 0; t < 4; t++) {
            #pragma unroll
            for (int rp = 0; rp < 2; rp++) {
                unsigned d = (unsigned)f2bf(sv[t][2 * rp]) |
                             ((unsigned)f2bf(sv[t][2 * rp + 1]) << 16);
                ovrow[8 * t + 2 * quad + rp] = d;
            }
        }
        __builtin_amdgcn_s_waitcnt(0xC07F);   // lgkmcnt(0): own-row pack writes complete
        #pragma unroll
        for (int kh = 0; kh < 2; kh++) {
            uint4 pd = *(const uint4*)&ovrow[16 * kh + 4 * quad];
            short8 pa = *(short8*)&pd;
            #pragma unroll
            for (int t = 0; t < 2; t++) {
                short8 vb = *(const short8*)&vs[buf][t * 16 + m][kh * 32 + quad * 8];
                oacc[t] = __builtin_amdgcn_mfma_f32_16x16x32_bf16(pa, vb, oacc[t], 0, 0, 0);
            }
        }
        // stage next tile + expand next SPD into own ov rows (overwrites P remnants).
        if (jt + 1 < NT) {
            *(uint4*)&ks[buf ^ 1][krow][kcol] = kpre;
            *(uint4*)&vs[buf ^ 1][vrow][vcol] = vpre;
            const unsigned char* bb = (const unsigned char*)&bpre;
            #pragma unroll
            for (int g = 0; g < 4; g++) {
                f32x4 st;
                #pragma unroll
                for (int i2 = 0; i2 < 4; i2++)
                    st[i2] = __int_as_float(__builtin_amdgcn_ds_bpermute(
                        ((int)bb[g * 4 + i2]) << 2, __float_as_int(spd_reg)));
                *(f32x4*)&ov[erow][ecol + g * 4] = st;
            }
            buf ^= 1;
        }
    }
    #pragma unroll
    for (int t = 0; t < 2; t++)
        #pragma unroll
        for (int r = 0; r < 4; r++)
            part_O[((size_t)js * N_NODES + i0 + r0 + quad * 4 + r) * D_MODEL + hh * DH + t * 16 + m] =
                oacc[t][r];
    // l reduction: lanes {m, m+16, m+32, m+48} hold partials for q-row r0+m
    l_acc += __int_as_float(__builtin_amdgcn_ds_bpermute((lane ^ 16) << 2, __float_as_int(l_acc)));
    l_acc += __int_as_float(__builtin_amdgcn_ds_bpermute((lane ^ 32) << 2, __float_as_int(l_acc)));
    if (quad == 0)
        l_part[((size_t)js * NHEAD + hh) * N_NODES + i0 + r0 + m] = l_acc;
}

// 256-byte-aligned workspace allocation
#define WS_ALLOC(type, name, count) \
    type* name = (type*)base; base += (((size_t)(count) * sizeof(type)) + 255) & ~(size_t)255;

extern "C" void kernel_launch(void* const* d_in, const int* in_sizes, int n_in,
                              void* d_out, int out_size, void* d_ws, size_t ws_size,
                              hipStream_t stream) {
    const float* x          = (const float*)d_in[0];
    const int*   edge_index = (const int*)d_in[1];
    const int*   edge_types = (const int*)d_in[2];
    const float* pos        = (const float*)d_in[3];
    const float* W_emb      = (const float*)d_in[4];
    const float* b_emb      = (const float*)d_in[5];
    const float* Wq         = (const float*)d_in[6];
    const float* Wk         = (const float*)d_in[7];
    const float* Wv         = (const float*)d_in[8];
    const float* Wo         = (const float*)d_in[9];
    const float* bq         = (const float*)d_in[10];
    const float* bk         = (const float*)d_in[11];
    const float* bv         = (const float*)d_in[12];
    const float* bo         = (const float*)d_in[13];
    const float* spd_table  = (const float*)d_in[14];
    const float* edge_table = (const float*)d_in[15];
    const float* din_emb    = (const float*)d_in[16];
    const float* dout_emb   = (const float*)d_in[17];
    const float* ln1_g      = (const float*)d_in[18];
    const float* ln1_b      = (const float*)d_in[19];
    const float* ln2_g      = (const float*)d_in[20];
    const float* ln2_b      = (const float*)d_in[21];
    const float* W1         = (const float*)d_in[22];
    const float* b1         = (const float*)d_in[23];
    const float* W2         = (const float*)d_in[24];
    const float* b2         = (const float*)d_in[25];
    const float* W_out      = (const float*)d_in[26];
    const float* b_out      = (const float*)d_in[27];
    float* out = (float*)d_out;

    char* base = (char*)d_ws;
    WS_ALLOC(int, deg_out, N_NODES)
    WS_ALLOC(int, deg_in, N_NODES)
    WS_ALLOC(float, h, N_NODES * D_MODEL)
    WS_ALLOC(unsigned short, xb, N_NODES * D_MODEL)
    WS_ALLOC(unsigned short, qkvb, N_NODES * 768)
    WS_ALLOC(unsigned short, vbt, D_MODEL * N_NODES)
    WS_ALLOC(unsigned short, ffnb, N_NODES * D_FF)
    WS_ALLOC(unsigned char, bucket, (size_t)N_NODES * N_NODES)
    WS_ALLOC(unsigned short, qkvt, NLAYER * 768 * D_MODEL)
    WS_ALLOC(unsigned short, wot, NLAYER * D_MODEL * D_MODEL)
    WS_ALLOC(unsigned short, w1t, NLAYER * D_MODEL * D_FF)
    WS_ALLOC(unsigned short, w2t, NLAYER * D_FF * D_MODEL)
    WS_ALLOC(unsigned short, wembt, D_FEAT * D_MODEL)
    WS_ALLOC(unsigned short, woutt, D_MODEL * D_OUT)
    WS_ALLOC(float, bqkv, NLAYER * 768)
    WS_ALLOC(unsigned, hist, 65536)
    WS_ALLOC(unsigned, offsets, 65536)
    WS_ALLOC(unsigned, cursor, 65536)
    WS_ALLOC(unsigned, gend, 1024)
    WS_ALLOC(unsigned, gcursor, 1)
    WS_ALLOC(unsigned, packed, NEDGE)
    WS_ALLOC(float, part_O, (size_t)JSPLIT * N_NODES * D_MODEL)
    WS_ALLOC(float, l_part, (size_t)JSPLIT * NHEAD * N_NODES)

    // ---- prep ----
    mega_prep_kernel<<<5702, 256, 0, stream>>>(pos, bucket, hist, deg_out, deg_in, gcursor,
                                               Wq, Wk, Wv, Wo, W1, W2, W_emb, W_out,
                                               bq, bk, bv, qkvt, wot, w1t, w2t, wembt, woutt, bqkv);
    degree_hist_kernel<<<NEDGE / 256, 256, 0, stream>>>(edge_index, deg_out, deg_in, hist);
    edge_alloc_kernel<<<1024, 64, 0, stream>>>(hist, offsets, cursor, gend, gcursor);
    edge_scatter_kernel<<<NEDGE / 256, 256, 0, stream>>>(edge_index, edge_types, cursor, packed);

    // embed: h = x @ W_emb + b_emb (fp32 A, cast in staging; single-shot K=128)
    gemm_ss_kernel<128, 0, false, false, true><<<dim3(D_MODEL / 64, N_NODES / 32), 256, 0, stream>>>(
        x, wembt, b_emb, h, nullptr, D_MODEL, D_FEAT);

    for (int l = 0; l < NLAYER; l++) {
        centrality_ln_kernel<<<N_NODES, 256, 0, stream>>>(
            h, din_emb + (size_t)l * (MAXDEG + 1) * D_MODEL,
            dout_emb + (size_t)l * (MAXDEG + 1) * D_MODEL, deg_in, deg_out,
            ln1_g + l * D_MODEL, ln1_b + l * D_MODEL, xb);

        // QKV gemm single-shot; V-region -> vbt via LDS transpose
        gemm_qkv_kernel<<<dim3(768 / 64, N_NODES / 32), 256, 0, stream>>>(
            xb, qkvt + (size_t)l * 768 * D_MODEL, bqkv + l * 768, qkvb, vbt);

        flash_attn_kernel<<<dim3(N_NODES / 64, NHEAD, JSPLIT), 256, 0, stream>>>(
            qkvb, vbt, bucket, spd_table + (size_t)l * 11 * NHEAD,
            edge_table + (size_t)l * 8 * NHEAD, offsets, gend, packed, part_O, l_part);

        gemm_oproj_kernel<<<dim3(D_MODEL / 64, N_NODES / 32), 256, 0, stream>>>(
            part_O, l_part, wot + (size_t)l * D_MODEL * D_MODEL, bo + l * D_MODEL, h);

        layernorm_kernel<<<N_NODES, 256, 0, stream>>>(h, ln2_g + l * D_MODEL, ln2_b + l * D_MODEL, xb);

        // FFN1 single-shot K=256, GELU, bf16 out
        gemm_ss_kernel<256, 1, false, true, false><<<dim3(D_FF / 64, N_NODES / 32), 256, 0, stream>>>(
            xb, w1t + (size_t)l * D_MODEL * D_FF, b1 + l * D_FF, nullptr, ffnb, D_FF, D_MODEL);

        // FFN2: K=1024 looped in KSTEP=256 chunks (7 barriers vs 32)
        gemm_ss_kernel<256, 0, true, false, false><<<dim3(D_MODEL / 64, N_NODES / 32), 256, 0, stream>>>(
            ffnb, w2t + (size_t)l * D_FF * D_MODEL, b2 + l * D_MODEL, h, nullptr, D_MODEL, D_FF);
    }

    // final: out = h @ W_out + b_out (fp32 A, cast in staging; single-shot K=256)
    gemm_ss_kernel<256, 0, false, false, true><<<dim3(D_OUT / 64, N_NODES / 32), 256, 0, stream>>>(
        h, woutt, b_out, out, nullptr, D_OUT, D_MODEL);
}

// Round 15
// 290.058 us; speedup vs baseline: 1.0938x; 1.0062x over previous
//
#include <hip/hip_runtime.h>
#include <math.h>

#define N_NODES 2048
#define D_MODEL 256
#define D_FEAT 128
#define NHEAD 8
#define DH 32
#define NLAYER 2
#define NEDGE 65536
#define D_FF 1024
#define D_OUT 128
#define MAXDEG 512
#define JSPLIT 4

typedef __attribute__((ext_vector_type(8))) short short8;
typedef __attribute__((ext_vector_type(4))) float f32x4;
typedef __attribute__((ext_vector_type(4))) unsigned short u16x4;

__device__ __forceinline__ unsigned short f2bf(float f) {
    unsigned u = __float_as_uint(f);
    unsigned r = (u + 0x7FFFu + ((u >> 16) & 1u)) >> 16;
    return (unsigned short)r;
}

// ---------------- mega prep: bucket table + zeroing + all weight transposes ----------------
__device__ __forceinline__ void wt_tile(const float* __restrict__ W, unsigned short* __restrict__ Wt,
                                        int K, int Nc, int n0, int k0, int tid,
                                        unsigned short (*tile)[33]) {
    int r = tid >> 3, cg = (tid & 7) * 4;
    float4 w4 = *(const float4*)&W[(size_t)(k0 + r) * Nc + n0 + cg];
    tile[r][cg + 0] = f2bf(w4.x); tile[r][cg + 1] = f2bf(w4.y);
    tile[r][cg + 2] = f2bf(w4.z); tile[r][cg + 3] = f2bf(w4.w);
    __syncthreads();
    int c = tid >> 3, rg = (tid & 7) * 4;
    u16x4 o;
    #pragma unroll
    for (int j = 0; j < 4; j++) o[j] = tile[rg + j][c];
    *(u16x4*)&Wt[(size_t)(n0 + c) * K + k0 + rg] = o;
}

__global__ void mega_prep_kernel(const float* __restrict__ pos, unsigned char* __restrict__ bucket,
                                 unsigned* __restrict__ hist, int* __restrict__ deg_out,
                                 int* __restrict__ deg_in, unsigned* __restrict__ gcursor,
                                 const float* __restrict__ Wq, const float* __restrict__ Wk,
                                 const float* __restrict__ Wv, const float* __restrict__ Wo,
                                 const float* __restrict__ W1, const float* __restrict__ W2,
                                 const float* __restrict__ W_emb, const float* __restrict__ W_out,
                                 const float* __restrict__ bq, const float* __restrict__ bk,
                                 const float* __restrict__ bv,
                                 unsigned short* __restrict__ qkvt, unsigned short* __restrict__ wot,
                                 unsigned short* __restrict__ w1t, unsigned short* __restrict__ w2t,
                                 unsigned short* __restrict__ wembt, unsigned short* __restrict__ woutt,
                                 float* __restrict__ bqkv) {
    __shared__ unsigned short tile[32][33];
    int b = blockIdx.x, tid = threadIdx.x;
    if (b < 4096) {
        int i = b * 256 + tid;
        float4 p = *(const float4*)&pos[(size_t)i * 4];
        unsigned b0 = (unsigned)fminf(fmaxf(p.x * 10.f + 0.5f, 0.f), 10.f);
        unsigned b1 = (unsigned)fminf(fmaxf(p.y * 10.f + 0.5f, 0.f), 10.f);
        unsigned b2 = (unsigned)fminf(fmaxf(p.z * 10.f + 0.5f, 0.f), 10.f);
        unsigned b3 = (unsigned)fminf(fmaxf(p.w * 10.f + 0.5f, 0.f), 10.f);
        ((unsigned*)bucket)[i] = b0 | (b1 << 8) | (b2 << 16) | (b3 << 24);
        if (b < 64) {
            #pragma unroll
            for (int k = 0; k < 4; k++) hist[b * 1024 + k * 256 + tid] = 0;
        } else if (b == 64) {
            #pragma unroll
            for (int k = 0; k < 8; k++) deg_out[k * 256 + tid] = 0;
            #pragma unroll
            for (int k = 0; k < 8; k++) deg_in[k * 256 + tid] = 0;
            if (tid == 0) *gcursor = 0;
        }
        return;
    }
    int bb = b - 4096;
    if (bb < 512) {
        int z = bb >> 6, t = bb & 63;
        int l = z >> 2, which = z & 3;
        const float* W = (which == 0 ? Wq : which == 1 ? Wk : which == 2 ? Wv : Wo) + (size_t)l * 65536;
        unsigned short* dst = (which < 3) ? qkvt + (size_t)l * 196608 + which * 65536
                                          : wot + (size_t)l * 65536;
        wt_tile(W, dst, 256, 256, (t & 7) * 32, (t >> 3) * 32, tid, tile);
    } else if (bb < 1024) {
        int b2 = bb - 512, l = b2 >> 8, t = b2 & 255;
        wt_tile(W1 + (size_t)l * D_MODEL * D_FF, w1t + (size_t)l * D_MODEL * D_FF,
                D_MODEL, D_FF, (t & 31) * 32, (t >> 5) * 32, tid, tile);
    } else if (bb < 1536) {
        int b3 = bb - 1024, l = b3 >> 8, t = b3 & 255;
        wt_tile(W2 + (size_t)l * D_FF * D_MODEL, w2t + (size_t)l * D_FF * D_MODEL,
                D_FF, D_MODEL, (t & 7) * 32, (t >> 3) * 32, tid, tile);
    } else if (bb < 1568) {
        int b4 = bb - 1536;
        wt_tile(W_emb, wembt, D_FEAT, D_MODEL, (b4 & 7) * 32, (b4 >> 3) * 32, tid, tile);
    } else if (bb < 1600) {
        int b5 = bb - 1568;
        wt_tile(W_out, woutt, D_MODEL, D_OUT, (b5 & 3) * 32, (b5 >> 2) * 32, tid, tile);
    } else {
        int i = (bb - 1600) * 256 + tid;
        if (i < NLAYER * 768) {
            int l = i / 768, j = i % 768;
            const float* src = j < 256 ? bq : j < 512 ? bk : bv;
            bqkv[i] = src[l * 256 + (j & 255)];
        }
    }
}

// ---------------- degree + edge histogram ----------------
__global__ void degree_hist_kernel(const int* __restrict__ ei,
                                   int* __restrict__ deg_out, int* __restrict__ deg_in,
                                   unsigned* __restrict__ hist) {
    int e = blockIdx.x * 256 + threadIdx.x;
    if (e < NEDGE) {
        int src = ei[e], dst = ei[NEDGE + e];
        atomicAdd(&deg_out[src], 1);
        atomicAdd(&deg_in[dst], 1);
        atomicAdd(&hist[(src >> 6) * 2048 + dst], 1);
    }
}

// ---------------- single-kernel slab allocator (per-64-key-group slabs) ----------------
__global__ void edge_alloc_kernel(const unsigned* __restrict__ hist,
                                  unsigned* __restrict__ offsets, unsigned* __restrict__ cursor,
                                  unsigned* __restrict__ gend, unsigned* __restrict__ gcursor) {
    int g = blockIdx.x;
    int t = threadIdx.x;
    unsigned v = hist[g * 64 + t];
    unsigned inc = v;
    #pragma unroll
    for (int off = 1; off < 64; off <<= 1) {
        unsigned u = __shfl_up(inc, off);
        if (t >= off) inc += u;
    }
    unsigned total = __shfl(inc, 63);
    unsigned base = 0;
    if (t == 63) base = atomicAdd(gcursor, total);
    base = __shfl(base, 63);
    unsigned o = base + inc - v;
    offsets[g * 64 + t] = o;
    cursor[g * 64 + t] = o;
    if (t == 63) gend[g] = base + total;
}

__global__ void edge_scatter_kernel(const int* __restrict__ ei, const int* __restrict__ etypes,
                                    unsigned* __restrict__ cursor, unsigned* __restrict__ packed) {
    int e = blockIdx.x * 256 + threadIdx.x;
    if (e < NEDGE) {
        int src = ei[e], dst = ei[NEDGE + e];
        int key = (src >> 6) * 2048 + dst;
        unsigned pos = atomicAdd(&cursor[key], 1);
        packed[pos] = (unsigned)dst | ((unsigned)(src & 63) << 11) | ((unsigned)etypes[e] << 17);
    }
}

// ---------------- fused centrality + layernorm1: wave-per-row, barrier-free ----------------
// 64 lanes x float4 = 256 cols; 6-step shfl_xor reduce; var = E[x^2]-mu^2 (R7-validated).
__global__ void centrality_ln_kernel(float* __restrict__ h,
                                     const float* __restrict__ din_l,
                                     const float* __restrict__ dout_l,
                                     const int* __restrict__ deg_in,
                                     const int* __restrict__ deg_out,
                                     const float* __restrict__ g,
                                     const float* __restrict__ b,
                                     unsigned short* __restrict__ y) {
    int wv = threadIdx.x >> 6, lane = threadIdx.x & 63;
    int row = blockIdx.x * 4 + wv;
    int c = lane * 4;
    int di = min(max(deg_in[row], 0), MAXDEG);
    int dn = min(max(deg_out[row], 0), MAXDEG);
    float4 hv = *(const float4*)&h[(size_t)row * D_MODEL + c];
    float4 d1 = *(const float4*)&din_l[(size_t)di * D_MODEL + c];
    float4 d2 = *(const float4*)&dout_l[(size_t)dn * D_MODEL + c];
    hv.x += d1.x + d2.x; hv.y += d1.y + d2.y;
    hv.z += d1.z + d2.z; hv.w += d1.w + d2.w;
    *(float4*)&h[(size_t)row * D_MODEL + c] = hv;
    float sum = hv.x + hv.y + hv.z + hv.w;
    float ss = hv.x * hv.x + hv.y * hv.y + hv.z * hv.z + hv.w * hv.w;
    #pragma unroll
    for (int off = 1; off < 64; off <<= 1) {
        sum += __shfl_xor(sum, off);
        ss += __shfl_xor(ss, off);
    }
    float mu = sum * (1.0f / D_MODEL);
    float rstd = rsqrtf(ss * (1.0f / D_MODEL) - mu * mu + 1e-5f);
    float4 gv = *(const float4*)&g[c];
    float4 bv = *(const float4*)&b[c];
    u16x4 o;
    o[0] = f2bf((hv.x - mu) * rstd * gv.x + bv.x);
    o[1] = f2bf((hv.y - mu) * rstd * gv.y + bv.y);
    o[2] = f2bf((hv.z - mu) * rstd * gv.z + bv.z);
    o[3] = f2bf((hv.w - mu) * rstd * gv.w + bv.w);
    *(u16x4*)&y[(size_t)row * D_MODEL + c] = o;
}

// ---------------- layernorm2: wave-per-row, barrier-free ----------------
__global__ void layernorm_kernel(const float* __restrict__ x,
                                 const float* __restrict__ g,
                                 const float* __restrict__ b,
                                 unsigned short* __restrict__ y) {
    int wv = threadIdx.x >> 6, lane = threadIdx.x & 63;
    int row = blockIdx.x * 4 + wv;
    int c = lane * 4;
    float4 hv = *(const float4*)&x[(size_t)row * D_MODEL + c];
    float sum = hv.x + hv.y + hv.z + hv.w;
    float ss = hv.x * hv.x + hv.y * hv.y + hv.z * hv.z + hv.w * hv.w;
    #pragma unroll
    for (int off = 1; off < 64; off <<= 1) {
        sum += __shfl_xor(sum, off);
        ss += __shfl_xor(ss, off);
    }
    float mu = sum * (1.0f / D_MODEL);
    float rstd = rsqrtf(ss * (1.0f / D_MODEL) - mu * mu + 1e-5f);
    float4 gv = *(const float4*)&g[c];
    float4 bv = *(const float4*)&b[c];
    u16x4 o;
    o[0] = f2bf((hv.x - mu) * rstd * gv.x + bv.x);
    o[1] = f2bf((hv.y - mu) * rstd * gv.y + bv.y);
    o[2] = f2bf((hv.z - mu) * rstd * gv.z + bv.z);
    o[3] = f2bf((hv.w - mu) * rstd * gv.w + bv.w);
    *(u16x4*)&y[(size_t)row * D_MODEL + c] = o;
}

// ---------------- bf16 MFMA GEMM, 32x64 tile, SINGLE-SHOT K staging ----------------
template <int KSTEP, int ACT, bool RESID, bool OUTBF16, bool AFP32>
__global__ void gemm_ss_kernel(const void* __restrict__ Av,
                               const unsigned short* __restrict__ Wt,
                               const float* __restrict__ bias,
                               float* __restrict__ C, unsigned short* __restrict__ Cb,
                               int Nc, int K) {
    __shared__ __align__(16) unsigned short As[32][KSTEP + 8];
    __shared__ __align__(16) unsigned short Bs[64][KSTEP + 8];
    const unsigned short* A16 = (const unsigned short*)Av;
    const float* A32 = (const float*)Av;
    int tid = threadIdx.x;
    int m0 = blockIdx.y * 32, n0 = blockIdx.x * 64;
    int w = tid >> 6, lane = tid & 63;
    int rg = (w & 1) * 16, cg = (w >> 1) * 32;
    int m = lane & 15, quad = lane >> 4;
    f32x4 acc[2] = {{0.f, 0.f, 0.f, 0.f}, {0.f, 0.f, 0.f, 0.f}};
    int ar = tid >> 3, ac8 = (tid & 7) * 8;
    for (int k0 = 0; k0 < K; k0 += KSTEP) {
        if (k0) __syncthreads();
        if (AFP32) {
            #pragma unroll
            for (int j = 0; j < KSTEP / 64; j++) {
                const float* ap = &A32[(size_t)(m0 + ar) * K + k0 + ac8 + j * 64];
                float4 f0 = *(const float4*)ap;
                float4 f1 = *(const float4*)(ap + 4);
                u16x4 t0 = {f2bf(f0.x), f2bf(f0.y), f2bf(f0.z), f2bf(f0.w)};
                u16x4 t1 = {f2bf(f1.x), f2bf(f1.y), f2bf(f1.z), f2bf(f1.w)};
                *(u16x4*)&As[ar][ac8 + j * 64] = t0;
                *(u16x4*)&As[ar][ac8 + j * 64 + 4] = t1;
            }
        } else {
            #pragma unroll
            for (int j = 0; j < KSTEP / 64; j++)
                *(uint4*)&As[ar][ac8 + j * 64] =
                    *(const uint4*)&A16[(size_t)(m0 + ar) * K + k0 + ac8 + j * 64];
        }
        #pragma unroll
        for (int j = 0; j < KSTEP / 64; j++) {
            *(uint4*)&Bs[ar][ac8 + j * 64] =
                *(const uint4*)&Wt[(size_t)(n0 + ar) * K + k0 + ac8 + j * 64];
            *(uint4*)&Bs[ar + 32][ac8 + j * 64] =
                *(const uint4*)&Wt[(size_t)(n0 + 32 + ar) * K + k0 + ac8 + j * 64];
        }
        __syncthreads();
        #pragma unroll
        for (int ks = 0; ks < KSTEP / 32; ks++) {
            short8 a = *(const short8*)&As[rg + m][ks * 32 + quad * 8];
            #pragma unroll
            for (int t = 0; t < 2; t++) {
                short8 b = *(const short8*)&Bs[cg + t * 16 + m][ks * 32 + quad * 8];
                acc[t] = __builtin_amdgcn_mfma_f32_16x16x32_bf16(a, b, acc[t], 0, 0, 0);
            }
        }
    }
    #pragma unroll
    for (int t = 0; t < 2; t++) {
        #pragma unroll
        for (int reg = 0; reg < 4; reg++) {
            int row = m0 + rg + quad * 4 + reg;
            int col = n0 + cg + t * 16 + m;
            float val = acc[t][reg] + bias[col];
            if (ACT == 1) val = val * 0.5f * (1.0f + erff(val * 0.7071067811865476f));
            size_t idx = (size_t)row * Nc + col;
            if (RESID) val += C[idx];
            if (OUTBF16) Cb[idx] = f2bf(val);
            else C[idx] = val;
        }
    }
}

// ---------------- QKV GEMM: single-shot K=256; Q/K -> qkvb; V-region (n0>=512)
// transposed through LDS and stored coalesced into vbt[dh][node] ----------------
__global__ void gemm_qkv_kernel(const unsigned short* __restrict__ A,
                                const unsigned short* __restrict__ Wt,
                                const float* __restrict__ bias,
                                unsigned short* __restrict__ Cb,
                                unsigned short* __restrict__ vbt) {
    const int K = D_MODEL, Nc = 768;
    __shared__ __align__(16) unsigned short As[32][264];
    __shared__ __align__(16) unsigned short Bs[64][264];
    int tid = threadIdx.x;
    int m0 = blockIdx.y * 32, n0 = blockIdx.x * 64;
    int w = tid >> 6, lane = tid & 63;
    int rg = (w & 1) * 16, cg = (w >> 1) * 32;
    int m = lane & 15, quad = lane >> 4;
    f32x4 acc[2] = {{0.f, 0.f, 0.f, 0.f}, {0.f, 0.f, 0.f, 0.f}};
    int ar = tid >> 3, ac8 = (tid & 7) * 8;
    #pragma unroll
    for (int j = 0; j < 4; j++)
        *(uint4*)&As[ar][ac8 + j * 64] =
            *(const uint4*)&A[(size_t)(m0 + ar) * K + ac8 + j * 64];
    #pragma unroll
    for (int j = 0; j < 4; j++) {
        *(uint4*)&Bs[ar][ac8 + j * 64] =
            *(const uint4*)&Wt[(size_t)(n0 + ar) * K + ac8 + j * 64];
        *(uint4*)&Bs[ar + 32][ac8 + j * 64] =
            *(const uint4*)&Wt[(size_t)(n0 + 32 + ar) * K + ac8 + j * 64];
    }
    __syncthreads();
    #pragma unroll
    for (int ks = 0; ks < 8; ks++) {
        short8 a = *(const short8*)&As[rg + m][ks * 32 + quad * 8];
        #pragma unroll
        for (int t = 0; t < 2; t++) {
            short8 b = *(const short8*)&Bs[cg + t * 16 + m][ks * 32 + quad * 8];
            acc[t] = __builtin_amdgcn_mfma_f32_16x16x32_bf16(a, b, acc[t], 0, 0, 0);
        }
    }
    if (n0 >= 512) {
        __syncthreads();   // all waves done reading Bs
        // V region: transpose through Bs, coalesced store to vbt
        #pragma unroll
        for (int t = 0; t < 2; t++) {
            int cl = cg + t * 16 + m;                   // local col = V dim within tile
            float bcol = bias[n0 + cl];
            u16x4 tv;
            #pragma unroll
            for (int reg = 0; reg < 4; reg++) tv[reg] = f2bf(acc[t][reg] + bcol);
            *(u16x4*)&Bs[cl][rg + quad * 4] = tv;       // Bs[local col][local row]
        }
        __syncthreads();
        int rr = tid >> 2, cc = (tid & 3) * 8;
        uint4 o0 = *(const uint4*)&Bs[rr][cc];
        *(uint4*)&vbt[(size_t)(n0 - 512 + rr) * N_NODES + m0 + cc] = o0;
        return;
    }
    #pragma unroll
    for (int t = 0; t < 2; t++) {
        #pragma unroll
        for (int reg = 0; reg < 4; reg++) {
            int row = m0 + rg + quad * 4 + reg;
            int col = n0 + cg + t * 16 + m;
            Cb[(size_t)row * Nc + col] = f2bf(acc[t][reg] + bias[col]);
        }
    }
}

// ---------------- O-proj GEMM, single-shot K=256, in-staging merge: h += (ΣO/Σl)@Wo + bo ----
__global__ void gemm_oproj_kernel(const float* __restrict__ part_O,
                                  const float* __restrict__ l_part,
                                  const unsigned short* __restrict__ Wt,
                                  const float* __restrict__ bias,
                                  float* __restrict__ C) {
    __shared__ __align__(16) unsigned short As[32][264];
    __shared__ __align__(16) unsigned short Bs[64][264];
    int tid = threadIdx.x;
    int m0 = blockIdx.y * 32, n0 = blockIdx.x * 64;
    int w = tid >> 6, lane = tid & 63;
    int rg = (w & 1) * 16, cg = (w >> 1) * 32;
    int m = lane & 15, quad = lane >> 4;
    f32x4 acc[2] = {{0.f, 0.f, 0.f, 0.f}, {0.f, 0.f, 0.f, 0.f}};
    int ar = tid >> 3, ac8 = (tid & 7) * 8;
    int row = m0 + ar;
    #pragma unroll
    for (int j = 0; j < 4; j++) {
        int col = ac8 + j * 64;
        int hh = col >> 5;
        float L = 0.f;
        float o[8] = {0.f, 0.f, 0.f, 0.f, 0.f, 0.f, 0.f, 0.f};
        #pragma unroll
        for (int js = 0; js < JSPLIT; js++) {
            L += l_part[((size_t)js * NHEAD + hh) * N_NODES + row];
            const float* pp = &part_O[((size_t)js * N_NODES + row) * D_MODEL + col];
            float4 p0 = *(const float4*)pp;
            float4 p1 = *(const float4*)(pp + 4);
            o[0] += p0.x; o[1] += p0.y; o[2] += p0.z; o[3] += p0.w;
            o[4] += p1.x; o[5] += p1.y; o[6] += p1.z; o[7] += p1.w;
        }
        float inv = 1.0f / L;
        u16x4 t0, t1;
        #pragma unroll
        for (int jj = 0; jj < 4; jj++) { t0[jj] = f2bf(o[jj] * inv); t1[jj] = f2bf(o[jj + 4] * inv); }
        *(u16x4*)&As[ar][col] = t0;
        *(u16x4*)&As[ar][col + 4] = t1;
    }
    #pragma unroll
    for (int j = 0; j < 4; j++) {
        *(uint4*)&Bs[ar][ac8 + j * 64] =
            *(const uint4*)&Wt[(size_t)(n0 + ar) * D_MODEL + ac8 + j * 64];
        *(uint4*)&Bs[ar + 32][ac8 + j * 64] =
            *(const uint4*)&Wt[(size_t)(n0 + 32 + ar) * D_MODEL + ac8 + j * 64];
    }
    __syncthreads();
    #pragma unroll
    for (int ks = 0; ks < 8; ks++) {
        short8 a = *(const short8*)&As[rg + m][ks * 32 + quad * 8];
        #pragma unroll
        for (int t = 0; t < 2; t++) {
            short8 b = *(const short8*)&Bs[cg + t * 16 + m][ks * 32 + quad * 8];
            acc[t] = __builtin_amdgcn_mfma_f32_16x16x32_bf16(a, b, acc[t], 0, 0, 0);
        }
    }
    #pragma unroll
    for (int t = 0; t < 2; t++) {
        #pragma unroll
        for (int reg = 0; reg < 4; reg++) {
            int orow = m0 + rg + quad * 4 + reg;
            int ocol = n0 + cg + t * 16 + m;
            size_t idx = (size_t)orow * D_MODEL + ocol;
            C[idx] += acc[t][reg] + bias[ocol];
        }
    }
}

// ---------------- flash attention v5: swapped QK^T, no swizzle (proven R11) ----------------
// grid (N/64, H, JSPLIT), block 256 = 4 waves; wave w owns rows w*16..+16.
__global__ __launch_bounds__(256)
void flash_attn_kernel(const unsigned short* __restrict__ qkvb,
                       const unsigned short* __restrict__ vbt,
                       const unsigned char* __restrict__ bucket,
                       const float* __restrict__ spd_l,
                       const float* __restrict__ et_l,
                       const unsigned* __restrict__ offsets,
                       const unsigned* __restrict__ gend,
                       const unsigned* __restrict__ packed,
                       float* __restrict__ part_O,
                       float* __restrict__ l_part) {
    __shared__ __align__(16) unsigned short ks[2][64][40];
    __shared__ __align__(16) unsigned short vs[2][32][72];
    __shared__ __align__(16) float ov[64][68];
    __shared__ float et[8];

    int tid = threadIdx.x;
    int rb = blockIdx.x;
    int i0 = rb * 64;
    int hh = blockIdx.y;
    int js = blockIdx.z;
    int lane = tid & 63;
    if (tid < 8) et[tid] = et_l[tid * NHEAD + hh];
    float spd_reg = spd_l[(lane < 11 ? lane : 10) * NHEAD + hh];

    int w = tid >> 6;
    int m = lane & 15, quad = lane >> 4;
    int r0 = w * 16;
    short8 aq = *(const short8*)&qkvb[(size_t)(i0 + r0 + m) * 768 + hh * DH + quad * 8];
    float l_acc = 0.f;
    f32x4 oacc[2] = {{0.f, 0.f, 0.f, 0.f}, {0.f, 0.f, 0.f, 0.f}};
    const float scale = 0.17677669529663687f;
    const int NT = N_NODES / JSPLIT / 64;

    int krow = tid >> 2, kcol = (tid & 3) * 8;
    int vrow = tid >> 3, vcol = (tid & 7) * 8;
    int erow = r0 + (lane >> 2);          // wave-private SPD expand: own 16 rows
    int ecol = (lane & 3) * 16;

    int jbase = js * (N_NODES / JSPLIT);
    // tile 0: load + stage + expand (own rows)
    uint4 kpre = *(const uint4*)&qkvb[(size_t)(jbase + krow) * 768 + 256 + hh * DH + kcol];
    uint4 vpre = *(const uint4*)&vbt[(size_t)(hh * DH + vrow) * N_NODES + jbase + vcol];
    uint4 bpre = *(const uint4*)&bucket[(size_t)(i0 + erow) * N_NODES + jbase + ecol];
    *(uint4*)&ks[0][krow][kcol] = kpre;
    *(uint4*)&vs[0][vrow][vcol] = vpre;
    {
        const unsigned char* bb = (const unsigned char*)&bpre;
        #pragma unroll
        for (int g = 0; g < 4; g++) {
            f32x4 st;
            #pragma unroll
            for (int i2 = 0; i2 < 4; i2++)
                st[i2] = __int_as_float(__builtin_amdgcn_ds_bpermute(
                    ((int)bb[g * 4 + i2]) << 2, __float_as_int(spd_reg)));
            *(f32x4*)&ov[erow][ecol + g * 4] = st;
        }
    }

    int buf = 0;
    for (int jt = 0; jt < NT; jt++) {
        int j0 = jbase + jt * 64;
        __syncthreads();                    // B1: staging + own-row expansion visible to all
        // ---- cross-wave phase: per-edge bias scatter-add ----
        {
            unsigned key0 = (unsigned)rb * 2048 + j0;
            unsigned start = offsets[key0], end = gend[key0 >> 6];
            for (unsigned i = start + tid; i < end; i += 256) {
                unsigned p = packed[i];
                atomicAdd(&ov[(p >> 11) & 63][(p & 2047) - j0], et[(p >> 17) & 7]);
            }
        }
        // prefetch next tile during the atomic phase
        if (jt + 1 < NT) {
            int jn = j0 + 64;
            kpre = *(const uint4*)&qkvb[(size_t)(jn + krow) * 768 + 256 + hh * DH + kcol];
            vpre = *(const uint4*)&vbt[(size_t)(hh * DH + vrow) * N_NODES + jn + vcol];
            bpre = *(const uint4*)&bucket[(size_t)(i0 + erow) * N_NODES + jn + ecol];
        }
        __syncthreads();                    // B2: atomics complete
        // ---- wave-private phase: swapped QK (P row lane-local), bias f32x4, exp ----
        float sv[4][4];
        #pragma unroll
        for (int t = 0; t < 4; t++) {
            short8 bk8 = *(const short8*)&ks[buf][t * 16 + m][quad * 8];
            f32x4 z = {0.f, 0.f, 0.f, 0.f};
            // swapped: A=K rows (16t+m), B=Q rows (r0+m): D[k=4quad+r][q=m]
            f32x4 sacc = __builtin_amdgcn_mfma_f32_16x16x32_bf16(bk8, aq, z, 0, 0, 0);
            f32x4 bv = *(const f32x4*)&ov[r0 + m][t * 16 + quad * 4];
            #pragma unroll
            for (int r = 0; r < 4; r++) {
                float pv = __expf(sacc[r] * scale + bv[r]);
                sv[t][r] = pv;
                l_acc += pv;
            }
        }
        // pack P to bf16 dwords into own ov row (bias already consumed)
        unsigned* ovrow = (unsigned*)&ov[r0 + m][0];
        #pragma unroll
        for (int t = 0; t < 4; t++) {
            #pragma unroll
            for (int rp = 0; rp < 2; rp++) {
                unsigned d = (unsigned)f2bf(sv[t][2 * rp]) |
                             ((unsigned)f2bf(sv[t][2 * rp + 1]) << 16);
                ovrow[8 * t + 2 * quad + rp] = d;
            }
        }
        __builtin_amdgcn_s_waitcnt(0xC07F);   // lgkmcnt(0): own-row pack writes complete
        #pragma unroll
        for (int kh = 0; kh < 2; kh++) {
            uint4 pd = *(const uint4*)&ovrow[16 * kh + 4 * quad];
            short8 pa = *(short8*)&pd;
            #pragma unroll
            for (int t = 0; t < 2; t++) {
                short8 vb = *(const short8*)&vs[buf][t * 16 + m][kh * 32 + quad * 8];
                oacc[t] = __builtin_amdgcn_mfma_f32_16x16x32_bf16(pa, vb, oacc[t], 0, 0, 0);
            }
        }
        // stage next tile + expand next SPD into own ov rows (overwrites P remnants).
        if (jt + 1 < NT) {
            *(uint4*)&ks[buf ^ 1][krow][kcol] = kpre;
            *(uint4*)&vs[buf ^ 1][vrow][vcol] = vpre;
            const unsigned char* bb = (const unsigned char*)&bpre;
            #pragma unroll
            for (int g = 0; g < 4; g++) {
                f32x4 st;
                #pragma unroll
                for (int i2 = 0; i2 < 4; i2++)
                    st[i2] = __int_as_float(__builtin_amdgcn_ds_bpermute(
                        ((int)bb[g * 4 + i2]) << 2, __float_as_int(spd_reg)));
                *(f32x4*)&ov[erow][ecol + g * 4] = st;
            }
            buf ^= 1;
        }
    }
    #pragma unroll
    for (int t = 0; t < 2; t++)
        #pragma unroll
        for (int r = 0; r < 4; r++)
            part_O[((size_t)js * N_NODES + i0 + r0 + quad * 4 + r) * D_MODEL + hh * DH + t * 16 + m] =
                oacc[t][r];
    // l reduction: lanes {m, m+16, m+32, m+48} hold partials for q-row r0+m
    l_acc += __int_as_float(__builtin_amdgcn_ds_bpermute((lane ^ 16) << 2, __float_as_int(l_acc)));
    l_acc += __int_as_float(__builtin_amdgcn_ds_bpermute((lane ^ 32) << 2, __float_as_int(l_acc)));
    if (quad == 0)
        l_part[((size_t)js * NHEAD + hh) * N_NODES + i0 + r0 + m] = l_acc;
}

// 256-byte-aligned workspace allocation
#define WS_ALLOC(type, name, count) \
    type* name = (type*)base; base += (((size_t)(count) * sizeof(type)) + 255) & ~(size_t)255;

extern "C" void kernel_launch(void* const* d_in, const int* in_sizes, int n_in,
                              void* d_out, int out_size, void* d_ws, size_t ws_size,
                              hipStream_t stream) {
    const float* x          = (const float*)d_in[0];
    const int*   edge_index = (const int*)d_in[1];
    const int*   edge_types = (const int*)d_in[2];
    const float* pos        = (const float*)d_in[3];
    const float* W_emb      = (const float*)d_in[4];
    const float* b_emb      = (const float*)d_in[5];
    const float* Wq         = (const float*)d_in[6];
    const float* Wk         = (const float*)d_in[7];
    const float* Wv         = (const float*)d_in[8];
    const float* Wo         = (const float*)d_in[9];
    const float* bq         = (const float*)d_in[10];
    const float* bk         = (const float*)d_in[11];
    const float* bv         = (const float*)d_in[12];
    const float* bo         = (const float*)d_in[13];
    const float* spd_table  = (const float*)d_in[14];
    const float* edge_table = (const float*)d_in[15];
    const float* din_emb    = (const float*)d_in[16];
    const float* dout_emb   = (const float*)d_in[17];
    const float* ln1_g      = (const float*)d_in[18];
    const float* ln1_b      = (const float*)d_in[19];
    const float* ln2_g      = (const float*)d_in[20];
    const float* ln2_b      = (const float*)d_in[21];
    const float* W1         = (const float*)d_in[22];
    const float* b1         = (const float*)d_in[23];
    const float* W2         = (const float*)d_in[24];
    const float* b2         = (const float*)d_in[25];
    const float* W_out      = (const float*)d_in[26];
    const float* b_out      = (const float*)d_in[27];
    float* out = (float*)d_out;

    char* base = (char*)d_ws;
    WS_ALLOC(int, deg_out, N_NODES)
    WS_ALLOC(int, deg_in, N_NODES)
    WS_ALLOC(float, h, N_NODES * D_MODEL)
    WS_ALLOC(unsigned short, xb, N_NODES * D_MODEL)
    WS_ALLOC(unsigned short, qkvb, N_NODES * 768)
    WS_ALLOC(unsigned short, vbt, D_MODEL * N_NODES)
    WS_ALLOC(unsigned short, ffnb, N_NODES * D_FF)
    WS_ALLOC(unsigned char, bucket, (size_t)N_NODES * N_NODES)
    WS_ALLOC(unsigned short, qkvt, NLAYER * 768 * D_MODEL)
    WS_ALLOC(unsigned short, wot, NLAYER * D_MODEL * D_MODEL)
    WS_ALLOC(unsigned short, w1t, NLAYER * D_MODEL * D_FF)
    WS_ALLOC(unsigned short, w2t, NLAYER * D_FF * D_MODEL)
    WS_ALLOC(unsigned short, wembt, D_FEAT * D_MODEL)
    WS_ALLOC(unsigned short, woutt, D_MODEL * D_OUT)
    WS_ALLOC(float, bqkv, NLAYER * 768)
    WS_ALLOC(unsigned, hist, 65536)
    WS_ALLOC(unsigned, offsets, 65536)
    WS_ALLOC(unsigned, cursor, 65536)
    WS_ALLOC(unsigned, gend, 1024)
    WS_ALLOC(unsigned, gcursor, 1)
    WS_ALLOC(unsigned, packed, NEDGE)
    WS_ALLOC(float, part_O, (size_t)JSPLIT * N_NODES * D_MODEL)
    WS_ALLOC(float, l_part, (size_t)JSPLIT * NHEAD * N_NODES)

    // ---- prep ----
    mega_prep_kernel<<<5702, 256, 0, stream>>>(pos, bucket, hist, deg_out, deg_in, gcursor,
                                               Wq, Wk, Wv, Wo, W1, W2, W_emb, W_out,
                                               bq, bk, bv, qkvt, wot, w1t, w2t, wembt, woutt, bqkv);
    degree_hist_kernel<<<NEDGE / 256, 256, 0, stream>>>(edge_index, deg_out, deg_in, hist);
    edge_alloc_kernel<<<1024, 64, 0, stream>>>(hist, offsets, cursor, gend, gcursor);
    edge_scatter_kernel<<<NEDGE / 256, 256, 0, stream>>>(edge_index, edge_types, cursor, packed);

    // embed: h = x @ W_emb + b_emb (fp32 A, cast in staging; single-shot K=128)
    gemm_ss_kernel<128, 0, false, false, true><<<dim3(D_MODEL / 64, N_NODES / 32), 256, 0, stream>>>(
        x, wembt, b_emb, h, nullptr, D_MODEL, D_FEAT);

    for (int l = 0; l < NLAYER; l++) {
        centrality_ln_kernel<<<N_NODES / 4, 256, 0, stream>>>(
            h, din_emb + (size_t)l * (MAXDEG + 1) * D_MODEL,
            dout_emb + (size_t)l * (MAXDEG + 1) * D_MODEL, deg_in, deg_out,
            ln1_g + l * D_MODEL, ln1_b + l * D_MODEL, xb);

        // QKV gemm single-shot; V-region -> vbt via LDS transpose
        gemm_qkv_kernel<<<dim3(768 / 64, N_NODES / 32), 256, 0, stream>>>(
            xb, qkvt + (size_t)l * 768 * D_MODEL, bqkv + l * 768, qkvb, vbt);

        flash_attn_kernel<<<dim3(N_NODES / 64, NHEAD, JSPLIT), 256, 0, stream>>>(
            qkvb, vbt, bucket, spd_table + (size_t)l * 11 * NHEAD,
            edge_table + (size_t)l * 8 * NHEAD, offsets, gend, packed, part_O, l_part);

        gemm_oproj_kernel<<<dim3(D_MODEL / 64, N_NODES / 32), 256, 0, stream>>>(
            part_O, l_part, wot + (size_t)l * D_MODEL * D_MODEL, bo + l * D_MODEL, h);

        layernorm_kernel<<<N_NODES / 4, 256, 0, stream>>>(
            h, ln2_g + l * D_MODEL, ln2_b + l * D_MODEL, xb);

        // FFN1 single-shot K=256, GELU, bf16 out
        gemm_ss_kernel<256, 1, false, true, false><<<dim3(D_FF / 64, N_NODES / 32), 256, 0, stream>>>(
            xb, w1t + (size_t)l * D_MODEL * D_FF, b1 + l * D_FF, nullptr, ffnb, D_FF, D_MODEL);

        // FFN2: K=1024 looped in KSTEP=256 chunks
        gemm_ss_kernel<256, 0, true, false, false><<<dim3(D_MODEL / 64, N_NODES / 32), 256, 0, stream>>>(
            ffnb, w2t + (size_t)l * D_FF * D_MODEL, b2 + l * D_MODEL, h, nullptr, D_MODEL, D_FF);
    }

    // final: out = h @ W_out + b_out (fp32 A, cast in staging; single-shot K=256)
    gemm_ss_kernel<256, 0, false, false, true><<<dim3(D_OUT / 64, N_NODES / 32), 256, 0, stream>>>(
        h, woutt, b_out, out, nullptr, D_OUT, D_MODEL);
}